// Round 1
// baseline (10866.216 us; speedup 1.0000x reference)
//
#include <hip/hip_runtime.h>

#define IN_F 128
#define HID_F 64
#define OUT_F 32
#define ENC_NEG_INF 0x007FFFFFu

// ---------------- workspace layout (float offsets) ----------------
// zeroed region first (single memset)
#define OFF_OUT1   0          // 1,280,000  (20000 x 64) aggregation accum L1
#define OFF_OUT2   1280000    // 640,000    (20000 x 32) aggregation accum L2
#define OFF_D1     1920000    // 20,000     softmax denom L1
#define OFF_D2     1940000    // 20,000     softmax denom L2
#define OFF_SUM    1960000    // 64         mean-pool partials (pad)
#define ZERO_FLOATS 1960064
#define OFF_M1     1960064    // 20,000  (unsigned, encoded max)
#define OFF_M2     1980064    // 20,000
#define OFF_H1     2000064    // 1,280,000  h1 = x@W1
#define OFF_H2     3280064    // 640,000    h2 = relu(out1+b1)@W2
#define OFF_ES1    3920064    // 20,000
#define OFF_ED1    3940064
#define OFF_ES2    3960064
#define OFF_ED2    3980064
#define OFF_EBUF   4000064    // 660,000    per-edge e / p
#define OFF_ZX     4660064    // 20000*128 + 256 pad   LSTM input projection
// total = 7,220,320 floats = 28.9 MB

__device__ __forceinline__ unsigned enc_f(float f) {
  unsigned b = __float_as_uint(f);
  return (b & 0x80000000u) ? ~b : (b | 0x80000000u);
}
__device__ __forceinline__ float dec_f(unsigned u) {
  unsigned b = (u & 0x80000000u) ? (u & 0x7FFFFFFFu) : ~u;
  return __uint_as_float(b);
}

// init encoded -inf for segment-max buffers
__global__ void k_initm(unsigned* __restrict__ m1, unsigned* __restrict__ m2, int n) {
  int i = blockIdx.x * blockDim.x + threadIdx.x;
  if (i < n) { m1[i] = ENC_NEG_INF; m2[i] = ENC_NEG_INF; }
}

// h1 = x @ W1 ; es1 = h1 . a_src ; ed1 = h1 . a_dst   (one wave per node)
__global__ void k_gemm1(const float* __restrict__ x, const float* __restrict__ W1,
                        const float* __restrict__ a_src, const float* __restrict__ a_dst,
                        float* __restrict__ h1, float* __restrict__ es, float* __restrict__ ed) {
  int n = blockIdx.x;
  int f = threadIdx.x;           // 0..63
  const float* xr = x + n * IN_F;
  float acc = 0.f;
#pragma unroll 8
  for (int k = 0; k < IN_F; ++k) acc = fmaf(xr[k], W1[k * HID_F + f], acc);
  h1[n * HID_F + f] = acc;
  float s = acc * a_src[f];
  float d = acc * a_dst[f];
#pragma unroll
  for (int off = 32; off; off >>= 1) {
    s += __shfl_down(s, off, 64);
    d += __shfl_down(d, off, 64);
  }
  if (f == 0) { es[n] = s; ed[n] = d; }
}

// per-edge score e = leaky_relu(es[src]+ed[dst], 0.2); segment max via encoded atomicMax
__global__ void k_emax(const int* __restrict__ ei, const float* __restrict__ es,
                       const float* __restrict__ ed, float* __restrict__ ebuf,
                       unsigned* __restrict__ menc, int E, int EP) {
  int i = blockIdx.x * blockDim.x + threadIdx.x;
  if (i >= EP) return;
  int src, dst;
  if (i < E) { src = ei[i]; dst = ei[E + i]; } else { src = dst = i - E; }
  float e = es[src] + ed[dst];
  e = (e >= 0.f) ? e : 0.2f * e;
  ebuf[i] = e;
  atomicMax(&menc[dst], enc_f(e));
}

// p = exp(e - m[dst]); denom[dst] += p
__global__ void k_ep(const int* __restrict__ ei, float* __restrict__ ebuf,
                     const unsigned* __restrict__ menc, float* __restrict__ denom,
                     int E, int EP) {
  int i = blockIdx.x * blockDim.x + threadIdx.x;
  if (i >= EP) return;
  int dst = (i < E) ? ei[E + i] : (i - E);
  float p = __expf(ebuf[i] - dec_f(menc[dst]));
  ebuf[i] = p;
  atomicAdd(&denom[dst], p);
}

// out[dst] += (p/denom[dst]) * h[src]   — F lanes per edge, coalesced gather+atomic
template <int F>
__global__ void k_aggr(const int* __restrict__ ei, const float* __restrict__ ebuf,
                       const float* __restrict__ denom, const float* __restrict__ h,
                       float* __restrict__ out, int E, int EP) {
  int gt = blockIdx.x * blockDim.x + threadIdx.x;
  int lane = gt % F;
  int e = gt / F;
  if (e >= EP) return;
  int src, dst;
  if (e < E) { src = ei[e]; dst = ei[E + e]; } else { src = dst = e - E; }
  float alpha = ebuf[e] / denom[dst];
  atomicAdd(&out[dst * F + lane], alpha * h[src * F + lane]);
}

// h2 = relu(out1+b1) @ W2 ; es2/ed2 reductions.  64 threads = 2 nodes/block.
__global__ void k_gemm2(const float* __restrict__ out1, const float* __restrict__ b1,
                        const float* __restrict__ W2, const float* __restrict__ a_src,
                        const float* __restrict__ a_dst, float* __restrict__ h2,
                        float* __restrict__ es, float* __restrict__ ed, int N) {
  int lane = threadIdx.x;
  int f = lane & 31;
  int n = blockIdx.x * 2 + (lane >> 5);
  if (n >= N) return;
  const float* r = out1 + n * HID_F;
  float acc = 0.f;
#pragma unroll 8
  for (int k = 0; k < HID_F; ++k) {
    float v = r[k] + b1[k];
    v = v > 0.f ? v : 0.f;
    acc = fmaf(v, W2[k * OUT_F + f], acc);
  }
  h2[n * OUT_F + f] = acc;
  float s = acc * a_src[f];
  float d = acc * a_dst[f];
#pragma unroll
  for (int off = 16; off; off >>= 1) {
    s += __shfl_down(s, off, 32);
    d += __shfl_down(d, off, 32);
  }
  if (f == 0) { es[n] = s; ed[n] = d; }
}

// Zx[t][r] = b_ih[r] + b_hh[r] + sum_k W_ih[r][k] * (out2[t][k] + b2[k])
__global__ void k_zx(const float* __restrict__ out2, const float* __restrict__ b2,
                     const float* __restrict__ Wih, const float* __restrict__ bih,
                     const float* __restrict__ bhh, float* __restrict__ Zx) {
  int r = threadIdx.x;   // 0..127
  int t = blockIdx.x;
  const float* xr = out2 + t * OUT_F;
  float acc = bih[r] + bhh[r];
#pragma unroll
  for (int k = 0; k < OUT_F; ++k) acc = fmaf(xr[k] + b2[k], Wih[r * OUT_F + k], acc);
  Zx[t * 128 + r] = acc;
}

// mean-pool partial sums of (out2 + b2)
__global__ void k_mean(const float* __restrict__ out2, const float* __restrict__ b2,
                       float* __restrict__ sum, int N) {
  int k = threadIdx.x & 31;
  int row = threadIdx.x >> 5;   // 0..7
  float acc = 0.f;
  for (int n = blockIdx.x * 8 + row; n < N; n += gridDim.x * 8)
    acc += out2[n * OUT_F + k] + b2[k];
  __shared__ float s[256];
  s[threadIdx.x] = acc;
  __syncthreads();
  if (threadIdx.x < 32) {
    float tot = 0.f;
#pragma unroll
    for (int j = 0; j < 8; ++j) tot += s[j * 32 + k];
    atomicAdd(&sum[k], tot);
  }
}

// classification head: out[0] = sigmoid(relu(mean @ fc2_w1^T + b1) @ fc2_w2^T + b2)
__global__ void k_head(const float* __restrict__ sum, const float* __restrict__ w1,
                       const float* __restrict__ bb1, const float* __restrict__ w2,
                       const float* __restrict__ bb2, float* __restrict__ out, float invN) {
  if (threadIdx.x == 0 && blockIdx.x == 0) {
    float xc[32];
#pragma unroll
    for (int k = 0; k < 32; ++k) xc[k] = sum[k] * invN;
    float t2 = bb2[0];
    for (int j = 0; j < 16; ++j) {
      float a = bb1[j];
#pragma unroll
      for (int k = 0; k < 32; ++k) a = fmaf(w1[j * 32 + k], xc[k], a);
      a = a > 0.f ? a : 0.f;
      t2 = fmaf(w2[j], a, t2);
    }
    out[0] = 1.f / (1.f + __expf(-t2));
  }
}

// sequential LSTM: single wave. lane l owns gate rows l and l+64.
// rows: i=0..31, f=32..63, g=64..95, o=96..127
__global__ void __launch_bounds__(64, 1) k_lstm(
    const float* __restrict__ Zx, const float* __restrict__ Whh,
    const float* __restrict__ fc1w, const float* __restrict__ fc1b,
    float* __restrict__ out, int N) {
  const int l = threadIdx.x;
  float wA[32], wB[32];
#pragma unroll
  for (int k = 0; k < 32; ++k) {
    wA[k] = Whh[l * 32 + k];
    wB[k] = Whh[(l + 64) * 32 + k];
  }
  float h = 0.f, c = 0.f;
  // 2-deep prefetch (Zx padded by 2 rows)
  float zA0 = Zx[l], zB0 = Zx[64 + l];
  float zA1 = Zx[128 + l], zB1 = Zx[192 + l];
  for (int t = 0; t < N; ++t) {
    float zA = zA0, zB = zB0;
    zA0 = zA1; zB0 = zB1;
    const float* nxt = Zx + (t + 2) * 128;
    zA1 = nxt[l];
    zB1 = nxt[64 + l];
#pragma unroll
    for (int k = 0; k < 32; ++k) {
      float hk = __uint_as_float(__builtin_amdgcn_readlane(__float_as_uint(h), k));
      zA = fmaf(wA[k], hk, zA);
      zB = fmaf(wB[k], hk, zB);
    }
    // lane l (<32): zA=i_l, zB=g_l ; lane l+32 holds f_l (zA), o_l (zB)
    float zf = __shfl_xor(zA, 32, 64);
    float zo = __shfl_xor(zB, 32, 64);
    float ig = 1.f / (1.f + __expf(-zA));
    float gg = 1.f - 2.f / (__expf(2.f * zB) + 1.f);   // tanh(zB)
    float fg = 1.f / (1.f + __expf(-zf));
    float og = 1.f / (1.f + __expf(-zo));
    c = fmaf(fg, c, ig * gg);
    float tc = 1.f - 2.f / (__expf(2.f * c) + 1.f);    // tanh(c)
    h = og * tc;
  }
  float v = (l < 32) ? fmaxf(c, 0.f) * fc1w[l] : 0.f;
#pragma unroll
  for (int off = 32; off; off >>= 1) v += __shfl_down(v, off, 64);
  if (l == 0) out[1] = v + fc1b[0];
}

extern "C" void kernel_launch(void* const* d_in, const int* in_sizes, int n_in,
                              void* d_out, int out_size, void* d_ws, size_t ws_size,
                              hipStream_t stream) {
  const float* x    = (const float*)d_in[0];
  const int*   ei   = (const int*)d_in[1];
  // d_in[2] edge_attr unused (edge_dim=None)
  const float* W1   = (const float*)d_in[3];
  const float* a1s  = (const float*)d_in[4];
  const float* a1d  = (const float*)d_in[5];
  const float* b1   = (const float*)d_in[6];
  const float* W2   = (const float*)d_in[7];
  const float* a2s  = (const float*)d_in[8];
  const float* a2d  = (const float*)d_in[9];
  const float* b2   = (const float*)d_in[10];
  const float* Wih  = (const float*)d_in[11];
  const float* Whh  = (const float*)d_in[12];
  const float* bih  = (const float*)d_in[13];
  const float* bhh  = (const float*)d_in[14];
  const float* fc1w = (const float*)d_in[15];
  const float* fc1b = (const float*)d_in[16];
  const float* f2w1 = (const float*)d_in[17];
  const float* f2b1 = (const float*)d_in[18];
  const float* f2w2 = (const float*)d_in[19];
  const float* f2b2 = (const float*)d_in[20];

  const int N  = in_sizes[0] / IN_F;   // 20000
  const int E  = in_sizes[1] / 2;      // 640000
  const int EP = E + N;                // 660000 (with self-loops)

  float* ws = (float*)d_ws;
  float*    out1  = ws + OFF_OUT1;
  float*    out2  = ws + OFF_OUT2;
  float*    d1    = ws + OFF_D1;
  float*    d2    = ws + OFF_D2;
  float*    sum   = ws + OFF_SUM;
  unsigned* m1    = (unsigned*)(ws + OFF_M1);
  unsigned* m2    = (unsigned*)(ws + OFF_M2);
  float*    h1    = ws + OFF_H1;
  float*    h2    = ws + OFF_H2;
  float*    es1   = ws + OFF_ES1;
  float*    ed1   = ws + OFF_ED1;
  float*    es2   = ws + OFF_ES2;
  float*    ed2   = ws + OFF_ED2;
  float*    ebuf  = ws + OFF_EBUF;
  float*    Zx    = ws + OFF_ZX;

  // zero accumulators (out1,out2,denoms,sum are contiguous at ws start)
  hipMemsetAsync(d_ws, 0, (size_t)ZERO_FLOATS * 4, stream);
  k_initm<<<(N + 255) / 256, 256, 0, stream>>>(m1, m2, N);

  // ---- GAT layer 1 ----
  k_gemm1<<<N, 64, 0, stream>>>(x, W1, a1s, a1d, h1, es1, ed1);
  int eb = (EP + 255) / 256;
  k_emax<<<eb, 256, 0, stream>>>(ei, es1, ed1, ebuf, m1, E, EP);
  k_ep<<<eb, 256, 0, stream>>>(ei, ebuf, m1, d1, E, EP);
  k_aggr<64><<<((size_t)EP * 64 + 255) / 256, 256, 0, stream>>>(ei, ebuf, d1, h1, out1, E, EP);

  // ---- GAT layer 2 (relu + b1 fused into GEMM input) ----
  k_gemm2<<<(N + 1) / 2, 64, 0, stream>>>(out1, b1, W2, a2s, a2d, h2, es2, ed2, N);
  k_emax<<<eb, 256, 0, stream>>>(ei, es2, ed2, ebuf, m2, E, EP);
  k_ep<<<eb, 256, 0, stream>>>(ei, ebuf, m2, d2, E, EP);
  k_aggr<32><<<((size_t)EP * 32 + 255) / 256, 256, 0, stream>>>(ei, ebuf, d2, h2, out2, E, EP);

  // ---- LSTM input projection + mean pool + heads ----
  k_zx<<<N, 128, 0, stream>>>(out2, b2, Wih, bih, bhh, Zx);
  k_mean<<<64, 256, 0, stream>>>(out2, b2, sum, N);
  k_head<<<1, 64, 0, stream>>>(sum, f2w1, f2b1, f2w2, f2b2, (float*)d_out, 1.f / (float)N);
  k_lstm<<<1, 64, 0, stream>>>(Zx, Whh, fc1w, fc1b, (float*)d_out, N);
}

// Round 2
// 10025.993 us; speedup vs baseline: 1.0838x; 1.0838x over previous
//
#include <hip/hip_runtime.h>

#define IN_F 128
#define HID_F 64
#define OUT_F 32
#define ENC_NEG_INF 0x007FFFFFu

// ---------------- workspace layout (float offsets) ----------------
// zeroed region first (single memset)
#define OFF_OUT1   0          // 1,280,000  (20000 x 64) aggregation accum L1
#define OFF_OUT2   1280000    // 640,000    (20000 x 32) aggregation accum L2
#define OFF_D1     1920000    // 20,000     softmax denom L1
#define OFF_D2     1940000    // 20,000     softmax denom L2
#define OFF_SUM    1960000    // 64         mean-pool partials (pad)
#define ZERO_FLOATS 1960064
#define OFF_M1     1960064    // 20,000  (unsigned, encoded max)
#define OFF_M2     1980064    // 20,000
#define OFF_H1     2000064    // 1,280,000  h1 = x@W1
#define OFF_H2     3280064    // 640,000    h2 = relu(out1+b1)@W2
#define OFF_ES1    3920064    // 20,000
#define OFF_ED1    3940064
#define OFF_ES2    3960064
#define OFF_ED2    3980064
#define OFF_EBUF   4000064    // 660,000    per-edge e / p
#define OFF_ZX     4660064    // 20000*128 + 256 pad   LSTM input projection (PERMUTED)
// total = 7,220,320 floats = 28.9 MB

__device__ __forceinline__ unsigned enc_f(float f) {
  unsigned b = __float_as_uint(f);
  return (b & 0x80000000u) ? ~b : (b | 0x80000000u);
}
__device__ __forceinline__ float dec_f(unsigned u) {
  unsigned b = (u & 0x80000000u) ? (u & 0x7FFFFFFFu) : ~u;
  return __uint_as_float(b);
}

// init encoded -inf for segment-max buffers
__global__ void k_initm(unsigned* __restrict__ m1, unsigned* __restrict__ m2, int n) {
  int i = blockIdx.x * blockDim.x + threadIdx.x;
  if (i < n) { m1[i] = ENC_NEG_INF; m2[i] = ENC_NEG_INF; }
}

// h1 = x @ W1 ; es1 = h1 . a_src ; ed1 = h1 . a_dst   (one wave per node)
__global__ void k_gemm1(const float* __restrict__ x, const float* __restrict__ W1,
                        const float* __restrict__ a_src, const float* __restrict__ a_dst,
                        float* __restrict__ h1, float* __restrict__ es, float* __restrict__ ed) {
  int n = blockIdx.x;
  int f = threadIdx.x;           // 0..63
  const float* xr = x + n * IN_F;
  float acc = 0.f;
#pragma unroll 8
  for (int k = 0; k < IN_F; ++k) acc = fmaf(xr[k], W1[k * HID_F + f], acc);
  h1[n * HID_F + f] = acc;
  float s = acc * a_src[f];
  float d = acc * a_dst[f];
#pragma unroll
  for (int off = 32; off; off >>= 1) {
    s += __shfl_down(s, off, 64);
    d += __shfl_down(d, off, 64);
  }
  if (f == 0) { es[n] = s; ed[n] = d; }
}

// per-edge score e = leaky_relu(es[src]+ed[dst], 0.2); segment max via encoded atomicMax
__global__ void k_emax(const int* __restrict__ ei, const float* __restrict__ es,
                       const float* __restrict__ ed, float* __restrict__ ebuf,
                       unsigned* __restrict__ menc, int E, int EP) {
  int i = blockIdx.x * blockDim.x + threadIdx.x;
  if (i >= EP) return;
  int src, dst;
  if (i < E) { src = ei[i]; dst = ei[E + i]; } else { src = dst = i - E; }
  float e = es[src] + ed[dst];
  e = (e >= 0.f) ? e : 0.2f * e;
  ebuf[i] = e;
  atomicMax(&menc[dst], enc_f(e));
}

// p = exp(e - m[dst]); denom[dst] += p
__global__ void k_ep(const int* __restrict__ ei, float* __restrict__ ebuf,
                     const unsigned* __restrict__ menc, float* __restrict__ denom,
                     int E, int EP) {
  int i = blockIdx.x * blockDim.x + threadIdx.x;
  if (i >= EP) return;
  int dst = (i < E) ? ei[E + i] : (i - E);
  float p = __expf(ebuf[i] - dec_f(menc[dst]));
  ebuf[i] = p;
  atomicAdd(&denom[dst], p);
}

// out[dst] += (p/denom[dst]) * h[src]   — F lanes per edge, coalesced gather+atomic
template <int F>
__global__ void k_aggr(const int* __restrict__ ei, const float* __restrict__ ebuf,
                       const float* __restrict__ denom, const float* __restrict__ h,
                       float* __restrict__ out, int E, int EP) {
  int gt = blockIdx.x * blockDim.x + threadIdx.x;
  int lane = gt % F;
  int e = gt / F;
  if (e >= EP) return;
  int src, dst;
  if (e < E) { src = ei[e]; dst = ei[E + e]; } else { src = dst = e - E; }
  float alpha = ebuf[e] / denom[dst];
  atomicAdd(&out[dst * F + lane], alpha * h[src * F + lane]);
}

// h2 = relu(out1+b1) @ W2 ; es2/ed2 reductions.  64 threads = 2 nodes/block.
__global__ void k_gemm2(const float* __restrict__ out1, const float* __restrict__ b1,
                        const float* __restrict__ W2, const float* __restrict__ a_src,
                        const float* __restrict__ a_dst, float* __restrict__ h2,
                        float* __restrict__ es, float* __restrict__ ed, int N) {
  int lane = threadIdx.x;
  int f = lane & 31;
  int n = blockIdx.x * 2 + (lane >> 5);
  if (n >= N) return;
  const float* r = out1 + n * HID_F;
  float acc = 0.f;
#pragma unroll 8
  for (int k = 0; k < HID_F; ++k) {
    float v = r[k] + b1[k];
    v = v > 0.f ? v : 0.f;
    acc = fmaf(v, W2[k * OUT_F + f], acc);
  }
  h2[n * OUT_F + f] = acc;
  float s = acc * a_src[f];
  float d = acc * a_dst[f];
#pragma unroll
  for (int off = 16; off; off >>= 1) {
    s += __shfl_down(s, off, 32);
    d += __shfl_down(d, off, 32);
  }
  if (f == 0) { es[n] = s; ed[n] = d; }
}

// Zx[t][pos(r)] = b_ih[r] + b_hh[r] + sum_k W_ih[r][k] * (out2[t][k] + b2[k])
// PERMUTED layout: pos = (r&31)*4 + (r>>5), so LSTM lane tid reads Zx[t*128 + (tid>>1)]
__global__ void k_zx(const float* __restrict__ out2, const float* __restrict__ b2,
                     const float* __restrict__ Wih, const float* __restrict__ bih,
                     const float* __restrict__ bhh, float* __restrict__ Zx) {
  int r = threadIdx.x;   // 0..127 (gate-major row: i=0..31,f=..63,g=..95,o=..127)
  int t = blockIdx.x;
  const float* xr = out2 + t * OUT_F;
  float acc = bih[r] + bhh[r];
#pragma unroll
  for (int k = 0; k < OUT_F; ++k) acc = fmaf(xr[k] + b2[k], Wih[r * OUT_F + k], acc);
  int pos = ((r & 31) << 2) | (r >> 5);   // j*4 + gate
  Zx[t * 128 + pos] = acc;
}

// mean-pool partial sums of (out2 + b2)
__global__ void k_mean(const float* __restrict__ out2, const float* __restrict__ b2,
                       float* __restrict__ sum, int N) {
  int k = threadIdx.x & 31;
  int row = threadIdx.x >> 5;   // 0..7
  float acc = 0.f;
  for (int n = blockIdx.x * 8 + row; n < N; n += gridDim.x * 8)
    acc += out2[n * OUT_F + k] + b2[k];
  __shared__ float s[256];
  s[threadIdx.x] = acc;
  __syncthreads();
  if (threadIdx.x < 32) {
    float tot = 0.f;
#pragma unroll
    for (int j = 0; j < 8; ++j) tot += s[j * 32 + k];
    atomicAdd(&sum[k], tot);
  }
}

// classification head: out[0] = sigmoid(relu(mean @ fc2_w1^T + b1) @ fc2_w2^T + b2)
__global__ void k_head(const float* __restrict__ sum, const float* __restrict__ w1,
                       const float* __restrict__ bb1, const float* __restrict__ w2,
                       const float* __restrict__ bb2, float* __restrict__ out, float invN) {
  if (threadIdx.x == 0 && blockIdx.x == 0) {
    float xc[32];
#pragma unroll
    for (int k = 0; k < 32; ++k) xc[k] = sum[k] * invN;
    float t2 = bb2[0];
    for (int j = 0; j < 16; ++j) {
      float a = bb1[j];
#pragma unroll
      for (int k = 0; k < 32; ++k) a = fmaf(w1[j * 32 + k], xc[k], a);
      a = a > 0.f ? a : 0.f;
      t2 = fmaf(w2[j], a, t2);
    }
    out[0] = 1.f / (1.f + __expf(-t2));
  }
}

// sequential LSTM: 4 waves (256 threads), one workgroup.
// tid = j*8 + gate*2 + half :  j=0..31 hidden idx, gate 0..3 (i,f,g,o), half = k-range
// Each lane: 16-MAC half-row dot product. half-combine via shfl_xor(1);
// gates exchanged in-wave via shfl_xor(2)/shfl_xor(4); cell update in gate==0 lanes;
// h broadcast via double-buffered LDS -> ONE barrier per step.
__global__ void __launch_bounds__(256, 1) k_lstm(
    const float* __restrict__ Zx, const float* __restrict__ Whh,
    const float* __restrict__ fc1w, const float* __restrict__ fc1b,
    float* __restrict__ out, int N) {
  const int tid  = threadIdx.x;
  const int j    = tid >> 3;
  const int g    = (tid >> 1) & 3;
  const int half = tid & 1;
  const int row  = g * 32 + j;

  float w[16];
#pragma unroll
  for (int k = 0; k < 16; ++k) w[k] = Whh[row * 32 + half * 16 + k];

  __shared__ float hb[2][32];
  __shared__ float cred[32];
  if (tid < 32) hb[1][tid] = 0.f;     // h(-1) lives in buf[1]
  __syncthreads();

  const int zidx = tid >> 1;          // 0..127, permuted Zx position
  float zx0 = Zx[zidx];
  float zx1 = Zx[128 + zidx];

  float c = 0.f;
  for (int t = 0; t < N; ++t) {
    // read h(t-1) from buf[(t-1)&1] == buf[(t+1)&1]
    const float4* hp = (const float4*)&hb[(t + 1) & 1][half * 16];
    float4 A = hp[0], B = hp[1], C4 = hp[2], D = hp[3];
    float zpre = zx0;
    zx0 = zx1;
    zx1 = Zx[(t + 2) * 128 + zidx];   // 2-deep prefetch (region padded)
    float a0 = fmaf(w[0],  A.x,  fmaf(w[1],  A.y,  fmaf(w[2],  A.z,  w[3]  * A.w)));
    float a1 = fmaf(w[4],  B.x,  fmaf(w[5],  B.y,  fmaf(w[6],  B.z,  w[7]  * B.w)));
    float a2 = fmaf(w[8],  C4.x, fmaf(w[9],  C4.y, fmaf(w[10], C4.z, w[11] * C4.w)));
    float a3 = fmaf(w[12], D.x,  fmaf(w[13], D.y,  fmaf(w[14], D.z,  w[15] * D.w)));
    float acc = (a0 + a1) + (a2 + a3);
    acc += __shfl_xor(acc, 1, 64);    // combine halves
    float z = zpre + acc;
    float zf_ = __shfl_xor(z, 2, 64);   // gate^1
    float zg_ = __shfl_xor(z, 4, 64);   // gate^2
    float zo_ = __shfl_xor(zf_, 4, 64); // gate^3
    if (g == 0) {
      // z=zi, zf_=zf, zg_=zg, zo_=zo
      float ig = 1.f / (1.f + __expf(-z));
      float fg = 1.f / (1.f + __expf(-zf_));
      float gg = 1.f - 2.f / (__expf(2.f * zg_) + 1.f);   // tanh
      float og = 1.f / (1.f + __expf(-zo_));
      c = fmaf(fg, c, ig * gg);
      float tc = 1.f - 2.f / (__expf(2.f * c) + 1.f);     // tanh(c)
      float h = og * tc;
      if (half == 0) hb[t & 1][j] = h;  // write h(t) into buf[t&1]
    }
    __syncthreads();                    // single barrier per step (double buffer)
  }

  if (g == 0 && half == 0) cred[j] = fmaxf(c, 0.f) * fc1w[j];
  __syncthreads();
  if (tid == 0) {
    float v = 0.f;
#pragma unroll
    for (int k = 0; k < 32; ++k) v += cred[k];
    out[1] = v + fc1b[0];
  }
}

extern "C" void kernel_launch(void* const* d_in, const int* in_sizes, int n_in,
                              void* d_out, int out_size, void* d_ws, size_t ws_size,
                              hipStream_t stream) {
  const float* x    = (const float*)d_in[0];
  const int*   ei   = (const int*)d_in[1];
  // d_in[2] edge_attr unused (edge_dim=None)
  const float* W1   = (const float*)d_in[3];
  const float* a1s  = (const float*)d_in[4];
  const float* a1d  = (const float*)d_in[5];
  const float* b1   = (const float*)d_in[6];
  const float* W2   = (const float*)d_in[7];
  const float* a2s  = (const float*)d_in[8];
  const float* a2d  = (const float*)d_in[9];
  const float* b2   = (const float*)d_in[10];
  const float* Wih  = (const float*)d_in[11];
  const float* Whh  = (const float*)d_in[12];
  const float* bih  = (const float*)d_in[13];
  const float* bhh  = (const float*)d_in[14];
  const float* fc1w = (const float*)d_in[15];
  const float* fc1b = (const float*)d_in[16];
  const float* f2w1 = (const float*)d_in[17];
  const float* f2b1 = (const float*)d_in[18];
  const float* f2w2 = (const float*)d_in[19];
  const float* f2b2 = (const float*)d_in[20];

  const int N  = in_sizes[0] / IN_F;   // 20000
  const int E  = in_sizes[1] / 2;      // 640000
  const int EP = E + N;                // 660000 (with self-loops)

  float* ws = (float*)d_ws;
  float*    out1  = ws + OFF_OUT1;
  float*    out2  = ws + OFF_OUT2;
  float*    d1    = ws + OFF_D1;
  float*    d2    = ws + OFF_D2;
  float*    sum   = ws + OFF_SUM;
  unsigned* m1    = (unsigned*)(ws + OFF_M1);
  unsigned* m2    = (unsigned*)(ws + OFF_M2);
  float*    h1    = ws + OFF_H1;
  float*    h2    = ws + OFF_H2;
  float*    es1   = ws + OFF_ES1;
  float*    ed1   = ws + OFF_ED1;
  float*    es2   = ws + OFF_ES2;
  float*    ed2   = ws + OFF_ED2;
  float*    ebuf  = ws + OFF_EBUF;
  float*    Zx    = ws + OFF_ZX;

  // zero accumulators (out1,out2,denoms,sum are contiguous at ws start)
  hipMemsetAsync(d_ws, 0, (size_t)ZERO_FLOATS * 4, stream);
  k_initm<<<(N + 255) / 256, 256, 0, stream>>>(m1, m2, N);

  // ---- GAT layer 1 ----
  k_gemm1<<<N, 64, 0, stream>>>(x, W1, a1s, a1d, h1, es1, ed1);
  int eb = (EP + 255) / 256;
  k_emax<<<eb, 256, 0, stream>>>(ei, es1, ed1, ebuf, m1, E, EP);
  k_ep<<<eb, 256, 0, stream>>>(ei, ebuf, m1, d1, E, EP);
  k_aggr<64><<<((size_t)EP * 64 + 255) / 256, 256, 0, stream>>>(ei, ebuf, d1, h1, out1, E, EP);

  // ---- GAT layer 2 (relu + b1 fused into GEMM input) ----
  k_gemm2<<<(N + 1) / 2, 64, 0, stream>>>(out1, b1, W2, a2s, a2d, h2, es2, ed2, N);
  k_emax<<<eb, 256, 0, stream>>>(ei, es2, ed2, ebuf, m2, E, EP);
  k_ep<<<eb, 256, 0, stream>>>(ei, ebuf, m2, d2, E, EP);
  k_aggr<32><<<((size_t)EP * 32 + 255) / 256, 256, 0, stream>>>(ei, ebuf, d2, h2, out2, E, EP);

  // ---- LSTM input projection + mean pool + heads ----
  k_zx<<<N, 128, 0, stream>>>(out2, b2, Wih, bih, bhh, Zx);
  k_mean<<<64, 256, 0, stream>>>(out2, b2, sum, N);
  k_head<<<1, 64, 0, stream>>>(sum, f2w1, f2b1, f2w2, f2b2, (float*)d_out, 1.f / (float)N);
  k_lstm<<<1, 256, 0, stream>>>(Zx, Whh, fc1w, fc1b, (float*)d_out, N);
}

// Round 3
// 7291.490 us; speedup vs baseline: 1.4903x; 1.3750x over previous
//
#include <hip/hip_runtime.h>

#define IN_F 128
#define HID_F 64
#define OUT_F 32
#define ENC_NEG_INF 0x007FFFFFu

// ---------------- workspace layout (float offsets) ----------------
// zeroed region first (single memset)
#define OFF_OUT1   0          // 1,280,000  (20000 x 64) aggregation accum L1
#define OFF_OUT2   1280000    // 640,000    (20000 x 32) aggregation accum L2
#define OFF_D1     1920000    // 20,000     softmax denom L1
#define OFF_D2     1940000    // 20,000     softmax denom L2
#define OFF_SUM    1960000    // 64         mean-pool partials (pad)
#define ZERO_FLOATS 1960064
#define OFF_M1     1960064    // 20,000  (unsigned, encoded max)
#define OFF_M2     1980064    // 20,000
#define OFF_H1     2000064    // 1,280,000  h1 = x@W1
#define OFF_H2     3280064    // 640,000    h2 = relu(out1+b1)@W2
#define OFF_ES1    3920064    // 20,000
#define OFF_ED1    3940064
#define OFF_ES2    3960064
#define OFF_ED2    3980064
#define OFF_EBUF   4000064    // 660,000    per-edge e / p
#define OFF_ZX     4660064    // 20000*128 + 256 pad   LSTM input projection (PERMUTED)
// total = 7,220,320 floats = 28.9 MB

__device__ __forceinline__ unsigned enc_f(float f) {
  unsigned b = __float_as_uint(f);
  return (b & 0x80000000u) ? ~b : (b | 0x80000000u);
}
__device__ __forceinline__ float dec_f(unsigned u) {
  unsigned b = (u & 0x80000000u) ? (u & 0x7FFFFFFFu) : ~u;
  return __uint_as_float(b);
}

// DPP quad_perm cross-lane (pure VALU, ~2 cyc): xor1=0xB1, xor2=0x4E, xor3=0x1B
template <int CTRL>
__device__ __forceinline__ float qperm(float x) {
  return __uint_as_float((unsigned)__builtin_amdgcn_update_dpp(
      0, (int)__float_as_uint(x), CTRL, 0xF, 0xF, true));
}

// init encoded -inf for segment-max buffers
__global__ void k_initm(unsigned* __restrict__ m1, unsigned* __restrict__ m2, int n) {
  int i = blockIdx.x * blockDim.x + threadIdx.x;
  if (i < n) { m1[i] = ENC_NEG_INF; m2[i] = ENC_NEG_INF; }
}

// h1 = x @ W1 ; es1 = h1 . a_src ; ed1 = h1 . a_dst   (one wave per node)
__global__ void k_gemm1(const float* __restrict__ x, const float* __restrict__ W1,
                        const float* __restrict__ a_src, const float* __restrict__ a_dst,
                        float* __restrict__ h1, float* __restrict__ es, float* __restrict__ ed) {
  int n = blockIdx.x;
  int f = threadIdx.x;           // 0..63
  const float* xr = x + n * IN_F;
  float acc = 0.f;
#pragma unroll 8
  for (int k = 0; k < IN_F; ++k) acc = fmaf(xr[k], W1[k * HID_F + f], acc);
  h1[n * HID_F + f] = acc;
  float s = acc * a_src[f];
  float d = acc * a_dst[f];
#pragma unroll
  for (int off = 32; off; off >>= 1) {
    s += __shfl_down(s, off, 64);
    d += __shfl_down(d, off, 64);
  }
  if (f == 0) { es[n] = s; ed[n] = d; }
}

// per-edge score e = leaky_relu(es[src]+ed[dst], 0.2); segment max via encoded atomicMax
__global__ void k_emax(const int* __restrict__ ei, const float* __restrict__ es,
                       const float* __restrict__ ed, float* __restrict__ ebuf,
                       unsigned* __restrict__ menc, int E, int EP) {
  int i = blockIdx.x * blockDim.x + threadIdx.x;
  if (i >= EP) return;
  int src, dst;
  if (i < E) { src = ei[i]; dst = ei[E + i]; } else { src = dst = i - E; }
  float e = es[src] + ed[dst];
  e = (e >= 0.f) ? e : 0.2f * e;
  ebuf[i] = e;
  atomicMax(&menc[dst], enc_f(e));
}

// p = exp(e - m[dst]); denom[dst] += p
__global__ void k_ep(const int* __restrict__ ei, float* __restrict__ ebuf,
                     const unsigned* __restrict__ menc, float* __restrict__ denom,
                     int E, int EP) {
  int i = blockIdx.x * blockDim.x + threadIdx.x;
  if (i >= EP) return;
  int dst = (i < E) ? ei[E + i] : (i - E);
  float p = __expf(ebuf[i] - dec_f(menc[dst]));
  ebuf[i] = p;
  atomicAdd(&denom[dst], p);
}

// out[dst] += (p/denom[dst]) * h[src]   — F lanes per edge, coalesced gather+atomic
template <int F>
__global__ void k_aggr(const int* __restrict__ ei, const float* __restrict__ ebuf,
                       const float* __restrict__ denom, const float* __restrict__ h,
                       float* __restrict__ out, int E, int EP) {
  int gt = blockIdx.x * blockDim.x + threadIdx.x;
  int lane = gt % F;
  int e = gt / F;
  if (e >= EP) return;
  int src, dst;
  if (e < E) { src = ei[e]; dst = ei[E + e]; } else { src = dst = e - E; }
  float alpha = ebuf[e] / denom[dst];
  atomicAdd(&out[dst * F + lane], alpha * h[src * F + lane]);
}

// h2 = relu(out1+b1) @ W2 ; es2/ed2 reductions.  64 threads = 2 nodes/block.
__global__ void k_gemm2(const float* __restrict__ out1, const float* __restrict__ b1,
                        const float* __restrict__ W2, const float* __restrict__ a_src,
                        const float* __restrict__ a_dst, float* __restrict__ h2,
                        float* __restrict__ es, float* __restrict__ ed, int N) {
  int lane = threadIdx.x;
  int f = lane & 31;
  int n = blockIdx.x * 2 + (lane >> 5);
  if (n >= N) return;
  const float* r = out1 + n * HID_F;
  float acc = 0.f;
#pragma unroll 8
  for (int k = 0; k < HID_F; ++k) {
    float v = r[k] + b1[k];
    v = v > 0.f ? v : 0.f;
    acc = fmaf(v, W2[k * OUT_F + f], acc);
  }
  h2[n * OUT_F + f] = acc;
  float s = acc * a_src[f];
  float d = acc * a_dst[f];
#pragma unroll
  for (int off = 16; off; off >>= 1) {
    s += __shfl_down(s, off, 32);
    d += __shfl_down(d, off, 32);
  }
  if (f == 0) { es[n] = s; ed[n] = d; }
}

// Zx[t][pos(r)] = b_ih[r] + b_hh[r] + sum_k W_ih[r][k] * (out2[t][k] + b2[k])
// PERMUTED layout: pos = (r&31)*4 + (r>>5); LSTM lane tid reads Zx[t*128 + tid]
// (tid -> row (tid&3)*32 + (tid>>2))
__global__ void k_zx(const float* __restrict__ out2, const float* __restrict__ b2,
                     const float* __restrict__ Wih, const float* __restrict__ bih,
                     const float* __restrict__ bhh, float* __restrict__ Zx) {
  int r = threadIdx.x;   // 0..127 (gate-major row: i=0..31,f=..63,g=..95,o=..127)
  int t = blockIdx.x;
  const float* xr = out2 + t * OUT_F;
  float acc = bih[r] + bhh[r];
#pragma unroll
  for (int k = 0; k < OUT_F; ++k) acc = fmaf(xr[k] + b2[k], Wih[r * OUT_F + k], acc);
  int pos = ((r & 31) << 2) | (r >> 5);   // j*4 + gate
  Zx[t * 128 + pos] = acc;
}

// mean-pool partial sums of (out2 + b2)
__global__ void k_mean(const float* __restrict__ out2, const float* __restrict__ b2,
                       float* __restrict__ sum, int N) {
  int k = threadIdx.x & 31;
  int row = threadIdx.x >> 5;   // 0..7
  float acc = 0.f;
  for (int n = blockIdx.x * 8 + row; n < N; n += gridDim.x * 8)
    acc += out2[n * OUT_F + k] + b2[k];
  __shared__ float s[256];
  s[threadIdx.x] = acc;
  __syncthreads();
  if (threadIdx.x < 32) {
    float tot = 0.f;
#pragma unroll
    for (int j = 0; j < 8; ++j) tot += s[j * 32 + k];
    atomicAdd(&sum[k], tot);
  }
}

// classification head: out[0] = sigmoid(relu(mean @ fc2_w1^T + b1) @ fc2_w2^T + b2)
__global__ void k_head(const float* __restrict__ sum, const float* __restrict__ w1,
                       const float* __restrict__ bb1, const float* __restrict__ w2,
                       const float* __restrict__ bb2, float* __restrict__ out, float invN) {
  if (threadIdx.x == 0 && blockIdx.x == 0) {
    float xc[32];
#pragma unroll
    for (int k = 0; k < 32; ++k) xc[k] = sum[k] * invN;
    float t2 = bb2[0];
    for (int j = 0; j < 16; ++j) {
      float a = bb1[j];
#pragma unroll
      for (int k = 0; k < 32; ++k) a = fmaf(w1[j * 32 + k], xc[k], a);
      a = a > 0.f ? a : 0.f;
      t2 = fmaf(w2[j], a, t2);
    }
    out[0] = 1.f / (1.f + __expf(-t2));
  }
}

// sequential LSTM: 2 waves (128 threads), one workgroup.
// lane tid = j*4 + g : j = tid>>2 in [0,32), g = tid&3 (i,f,g,o). row = g*32+j.
// Full 32-MAC row per lane; gates of unit j live in ONE DPP QUAD ->
// exchange via quad_perm DPP (pure VALU). h broadcast via double-buffered LDS,
// single barrier per step. Zx prefetched 4 deep (permuted layout, coalesced).
__global__ void __launch_bounds__(128, 1) k_lstm(
    const float* __restrict__ Zx, const float* __restrict__ Whh,
    const float* __restrict__ fc1w, const float* __restrict__ fc1b,
    float* __restrict__ out, int N) {
  const int tid = threadIdx.x;   // 0..127
  const int g   = tid & 3;
  const int j   = tid >> 2;      // 0..31
  const int row = g * 32 + j;

  float w[32];
#pragma unroll
  for (int k = 0; k < 32; ++k) w[k] = Whh[row * 32 + k];

  __shared__ __align__(16) float hb[2][32];
  __shared__ float cred[32];
  if (tid < 32) hb[1][tid] = 0.f;   // h(-1) lives in buf[1]
  __syncthreads();

  const float* pz = Zx + tid;
  float zr[4];
#pragma unroll
  for (int s = 0; s < 4; ++s) zr[s] = pz[s * 128];

  float c = 0.f;
  for (int t = 0; t < N; t += 4) {
#pragma unroll
    for (int s = 0; s < 4; ++s) {
      const int u = t + s;
      // h(u-1) is in buf[(u-1)&1] == buf[(u+1)&1]; broadcast reads (same addr all lanes)
      const float4* hp = (const float4*)hb[(u + 1) & 1];
      float4 A = hp[0], B = hp[1], C4 = hp[2], D = hp[3];
      float4 E4 = hp[4], F4 = hp[5], G4 = hp[6], H4 = hp[7];
      float z = zr[s];
      int nu = u + 4; nu = (nu < N) ? nu : 0;   // clamped 4-deep prefetch
      zr[s] = pz[nu * 128];
      float a0 = fmaf(w[0], A.x, fmaf(w[1], A.y, fmaf(w[2], A.z, w[3] * A.w)));
      a0 = fmaf(w[4], B.x, fmaf(w[5], B.y, fmaf(w[6], B.z, fmaf(w[7], B.w, a0))));
      float a1 = fmaf(w[8], C4.x, fmaf(w[9], C4.y, fmaf(w[10], C4.z, w[11] * C4.w)));
      a1 = fmaf(w[12], D.x, fmaf(w[13], D.y, fmaf(w[14], D.z, fmaf(w[15], D.w, a1))));
      float a2 = fmaf(w[16], E4.x, fmaf(w[17], E4.y, fmaf(w[18], E4.z, w[19] * E4.w)));
      a2 = fmaf(w[20], F4.x, fmaf(w[21], F4.y, fmaf(w[22], F4.z, fmaf(w[23], F4.w, a2))));
      float a3 = fmaf(w[24], G4.x, fmaf(w[25], G4.y, fmaf(w[26], G4.z, w[27] * G4.w)));
      a3 = fmaf(w[28], H4.x, fmaf(w[29], H4.y, fmaf(w[30], H4.z, fmaf(w[31], H4.w, a3))));
      z += (a0 + a1) + (a2 + a3);
      // gate exchange inside the quad: i,f,g,o at g=0..3
      float x1 = qperm<0xB1>(z);   // xor1
      float x2 = qperm<0x4E>(z);   // xor2
      float x3 = qperm<0x1B>(z);   // xor3
      // in g==0 lanes: z=zi, x1=zf, x2=zg, x3=zo (other lanes compute garbage, unused)
      float ig = 1.f / (1.f + __expf(-z));
      float fg = 1.f / (1.f + __expf(-x1));
      float gg = 1.f - 2.f / (__expf(2.f * x2) + 1.f);   // tanh
      float og = 1.f / (1.f + __expf(-x3));
      c = fmaf(fg, c, ig * gg);
      float tc = 1.f - 2.f / (__expf(2.f * c) + 1.f);    // tanh(c)
      float h = og * tc;
      if (g == 0) hb[u & 1][j] = h;   // write h(u) into buf[u&1]
      __syncthreads();                // single barrier per step (double buffer)
    }
  }

  if (g == 0) cred[j] = fmaxf(c, 0.f) * fc1w[j];
  __syncthreads();
  if (tid == 0) {
    float v = 0.f;
#pragma unroll
    for (int k = 0; k < 32; ++k) v += cred[k];
    out[1] = v + fc1b[0];
  }
}

extern "C" void kernel_launch(void* const* d_in, const int* in_sizes, int n_in,
                              void* d_out, int out_size, void* d_ws, size_t ws_size,
                              hipStream_t stream) {
  const float* x    = (const float*)d_in[0];
  const int*   ei   = (const int*)d_in[1];
  // d_in[2] edge_attr unused (edge_dim=None)
  const float* W1   = (const float*)d_in[3];
  const float* a1s  = (const float*)d_in[4];
  const float* a1d  = (const float*)d_in[5];
  const float* b1   = (const float*)d_in[6];
  const float* W2   = (const float*)d_in[7];
  const float* a2s  = (const float*)d_in[8];
  const float* a2d  = (const float*)d_in[9];
  const float* b2   = (const float*)d_in[10];
  const float* Wih  = (const float*)d_in[11];
  const float* Whh  = (const float*)d_in[12];
  const float* bih  = (const float*)d_in[13];
  const float* bhh  = (const float*)d_in[14];
  const float* fc1w = (const float*)d_in[15];
  const float* fc1b = (const float*)d_in[16];
  const float* f2w1 = (const float*)d_in[17];
  const float* f2b1 = (const float*)d_in[18];
  const float* f2w2 = (const float*)d_in[19];
  const float* f2b2 = (const float*)d_in[20];

  const int N  = in_sizes[0] / IN_F;   // 20000
  const int E  = in_sizes[1] / 2;      // 640000
  const int EP = E + N;                // 660000 (with self-loops)

  float* ws = (float*)d_ws;
  float*    out1  = ws + OFF_OUT1;
  float*    out2  = ws + OFF_OUT2;
  float*    d1    = ws + OFF_D1;
  float*    d2    = ws + OFF_D2;
  float*    sum   = ws + OFF_SUM;
  unsigned* m1    = (unsigned*)(ws + OFF_M1);
  unsigned* m2    = (unsigned*)(ws + OFF_M2);
  float*    h1    = ws + OFF_H1;
  float*    h2    = ws + OFF_H2;
  float*    es1   = ws + OFF_ES1;
  float*    ed1   = ws + OFF_ED1;
  float*    es2   = ws + OFF_ES2;
  float*    ed2   = ws + OFF_ED2;
  float*    ebuf  = ws + OFF_EBUF;
  float*    Zx    = ws + OFF_ZX;

  // zero accumulators (out1,out2,denoms,sum are contiguous at ws start)
  hipMemsetAsync(d_ws, 0, (size_t)ZERO_FLOATS * 4, stream);
  k_initm<<<(N + 255) / 256, 256, 0, stream>>>(m1, m2, N);

  // ---- GAT layer 1 ----
  k_gemm1<<<N, 64, 0, stream>>>(x, W1, a1s, a1d, h1, es1, ed1);
  int eb = (EP + 255) / 256;
  k_emax<<<eb, 256, 0, stream>>>(ei, es1, ed1, ebuf, m1, E, EP);
  k_ep<<<eb, 256, 0, stream>>>(ei, ebuf, m1, d1, E, EP);
  k_aggr<64><<<((size_t)EP * 64 + 255) / 256, 256, 0, stream>>>(ei, ebuf, d1, h1, out1, E, EP);

  // ---- GAT layer 2 (relu + b1 fused into GEMM input) ----
  k_gemm2<<<(N + 1) / 2, 64, 0, stream>>>(out1, b1, W2, a2s, a2d, h2, es2, ed2, N);
  k_emax<<<eb, 256, 0, stream>>>(ei, es2, ed2, ebuf, m2, E, EP);
  k_ep<<<eb, 256, 0, stream>>>(ei, ebuf, m2, d2, E, EP);
  k_aggr<32><<<((size_t)EP * 32 + 255) / 256, 256, 0, stream>>>(ei, ebuf, d2, h2, out2, E, EP);

  // ---- LSTM input projection + mean pool + heads ----
  k_zx<<<N, 128, 0, stream>>>(out2, b2, Wih, bih, bhh, Zx);
  k_mean<<<64, 256, 0, stream>>>(out2, b2, sum, N);
  k_head<<<1, 64, 0, stream>>>(sum, f2w1, f2b1, f2w2, f2b2, (float*)d_out, 1.f / (float)N);
  k_lstm<<<1, 128, 0, stream>>>(Zx, Whh, fc1w, fc1b, (float*)d_out, N);
}

// Round 5
// 5850.785 us; speedup vs baseline: 1.8572x; 1.2462x over previous
//
#include <hip/hip_runtime.h>

#define IN_F 128
#define HID_F 64
#define OUT_F 32
#define ENC_NEG_INF 0x007FFFFFu

// ---------------- workspace layout (float offsets) ----------------
// zeroed region first (single memset)
#define OFF_OUT1   0          // 1,280,000  (20000 x 64) aggregation accum L1
#define OFF_OUT2   1280000    // 640,000    (20000 x 32) aggregation accum L2
#define OFF_D1     1920000    // 20,000     softmax denom L1
#define OFF_D2     1940000    // 20,000     softmax denom L2
#define OFF_SUM    1960000    // 64         mean-pool partials (pad)
#define ZERO_FLOATS 1960064
#define OFF_M1     1960064    // 20,000  (unsigned, encoded max)
#define OFF_M2     1980064    // 20,000
#define OFF_H1     2000064    // 1,280,000  h1 = x@W1
#define OFF_H2     3280064    // 640,000    h2 = relu(out1+b1)@W2
#define OFF_ES1    3920064    // 20,000
#define OFF_ED1    3940064
#define OFF_ES2    3960064
#define OFF_ED2    3980064
#define OFF_EBUF   4000064    // 660,000    per-edge e / p
#define OFF_ZX     4660064    // 20000*128 + 1024 pad   LSTM input projection (PACKED)
// total floats ~ 7,221,088 = 28.9 MB

__device__ __forceinline__ unsigned enc_f(float f) {
  unsigned b = __float_as_uint(f);
  return (b & 0x80000000u) ? ~b : (b | 0x80000000u);
}
__device__ __forceinline__ float dec_f(unsigned u) {
  unsigned b = (u & 0x80000000u) ? (u & 0x7FFFFFFFu) : ~u;
  return __uint_as_float(b);
}

// DPP quad_perm cross-lane (pure VALU): 0xB1 = swap within lane pairs (xor1)
template <int CTRL>
__device__ __forceinline__ float qperm(float x) {
  return __uint_as_float((unsigned)__builtin_amdgcn_update_dpp(
      0, (int)__float_as_uint(x), CTRL, 0xF, 0xF, true));
}

// init encoded -inf for segment-max buffers
__global__ void k_initm(unsigned* __restrict__ m1, unsigned* __restrict__ m2, int n) {
  int i = blockIdx.x * blockDim.x + threadIdx.x;
  if (i < n) { m1[i] = ENC_NEG_INF; m2[i] = ENC_NEG_INF; }
}

// h1 = x @ W1 ; es1 = h1 . a_src ; ed1 = h1 . a_dst   (one wave per node)
__global__ void k_gemm1(const float* __restrict__ x, const float* __restrict__ W1,
                        const float* __restrict__ a_src, const float* __restrict__ a_dst,
                        float* __restrict__ h1, float* __restrict__ es, float* __restrict__ ed) {
  int n = blockIdx.x;
  int f = threadIdx.x;           // 0..63
  const float* xr = x + n * IN_F;
  float acc = 0.f;
#pragma unroll 8
  for (int k = 0; k < IN_F; ++k) acc = fmaf(xr[k], W1[k * HID_F + f], acc);
  h1[n * HID_F + f] = acc;
  float s = acc * a_src[f];
  float d = acc * a_dst[f];
#pragma unroll
  for (int off = 32; off; off >>= 1) {
    s += __shfl_down(s, off, 64);
    d += __shfl_down(d, off, 64);
  }
  if (f == 0) { es[n] = s; ed[n] = d; }
}

// per-edge score e = leaky_relu(es[src]+ed[dst], 0.2); segment max via encoded atomicMax
__global__ void k_emax(const int* __restrict__ ei, const float* __restrict__ es,
                       const float* __restrict__ ed, float* __restrict__ ebuf,
                       unsigned* __restrict__ menc, int E, int EP) {
  int i = blockIdx.x * blockDim.x + threadIdx.x;
  if (i >= EP) return;
  int src, dst;
  if (i < E) { src = ei[i]; dst = ei[E + i]; } else { src = dst = i - E; }
  float e = es[src] + ed[dst];
  e = (e >= 0.f) ? e : 0.2f * e;
  ebuf[i] = e;
  atomicMax(&menc[dst], enc_f(e));
}

// p = exp(e - m[dst]); denom[dst] += p
__global__ void k_ep(const int* __restrict__ ei, float* __restrict__ ebuf,
                     const unsigned* __restrict__ menc, float* __restrict__ denom,
                     int E, int EP) {
  int i = blockIdx.x * blockDim.x + threadIdx.x;
  if (i >= EP) return;
  int dst = (i < E) ? ei[E + i] : (i - E);
  float p = __expf(ebuf[i] - dec_f(menc[dst]));
  ebuf[i] = p;
  atomicAdd(&denom[dst], p);
}

// out[dst] += (p/denom[dst]) * h[src]   — F lanes per edge, coalesced gather+atomic
template <int F>
__global__ void k_aggr(const int* __restrict__ ei, const float* __restrict__ ebuf,
                       const float* __restrict__ denom, const float* __restrict__ h,
                       float* __restrict__ out, int E, int EP) {
  int gt = blockIdx.x * blockDim.x + threadIdx.x;
  int lane = gt % F;
  int e = gt / F;
  if (e >= EP) return;
  int src, dst;
  if (e < E) { src = ei[e]; dst = ei[E + e]; } else { src = dst = e - E; }
  float alpha = ebuf[e] / denom[dst];
  atomicAdd(&out[dst * F + lane], alpha * h[src * F + lane]);
}

// h2 = relu(out1+b1) @ W2 ; es2/ed2 reductions.  64 threads = 2 nodes/block.
__global__ void k_gemm2(const float* __restrict__ out1, const float* __restrict__ b1,
                        const float* __restrict__ W2, const float* __restrict__ a_src,
                        const float* __restrict__ a_dst, float* __restrict__ h2,
                        float* __restrict__ es, float* __restrict__ ed, int N) {
  int lane = threadIdx.x;
  int f = lane & 31;
  int n = blockIdx.x * 2 + (lane >> 5);
  if (n >= N) return;
  const float* r = out1 + n * HID_F;
  float acc = 0.f;
#pragma unroll 8
  for (int k = 0; k < HID_F; ++k) {
    float v = r[k] + b1[k];
    v = v > 0.f ? v : 0.f;
    acc = fmaf(v, W2[k * OUT_F + f], acc);
  }
  h2[n * OUT_F + f] = acc;
  float s = acc * a_src[f];
  float d = acc * a_dst[f];
#pragma unroll
  for (int off = 16; off; off >>= 1) {
    s += __shfl_down(s, off, 32);
    d += __shfl_down(d, off, 32);
  }
  if (f == 0) { es[n] = s; ed[n] = d; }
}

// Zx packed for single-wave LSTM: row r (gate-major: i=0..31,f=..63,g=..95,o=..127)
//   j=r&31, gate=r>>5 ; p=gate&1, e=gate>>1 ; pos = j*4 + p*2 + e
// LSTM lane l=j*2+p reads float2 at t*128 + l*2 : .x = gate p (i/f), .y = gate 2+p (g/o)
__global__ void k_zx(const float* __restrict__ out2, const float* __restrict__ b2,
                     const float* __restrict__ Wih, const float* __restrict__ bih,
                     const float* __restrict__ bhh, float* __restrict__ Zx) {
  int r = threadIdx.x;   // 0..127
  int t = blockIdx.x;
  const float* xr = out2 + t * OUT_F;
  float acc = bih[r] + bhh[r];
#pragma unroll
  for (int k = 0; k < OUT_F; ++k) acc = fmaf(xr[k] + b2[k], Wih[r * OUT_F + k], acc);
  int pos = ((r & 31) << 2) | (((r >> 5) & 1) << 1) | (r >> 6);
  Zx[t * 128 + pos] = acc;
}

// mean-pool partial sums of (out2 + b2)
__global__ void k_mean(const float* __restrict__ out2, const float* __restrict__ b2,
                       float* __restrict__ sum, int N) {
  int k = threadIdx.x & 31;
  int row = threadIdx.x >> 5;   // 0..7
  float acc = 0.f;
  for (int n = blockIdx.x * 8 + row; n < N; n += gridDim.x * 8)
    acc += out2[n * OUT_F + k] + b2[k];
  __shared__ float s[256];
  s[threadIdx.x] = acc;
  __syncthreads();
  if (threadIdx.x < 32) {
    float tot = 0.f;
#pragma unroll
    for (int j = 0; j < 8; ++j) tot += s[j * 32 + k];
    atomicAdd(&sum[k], tot);
  }
}

// classification head: out[0] = sigmoid(relu(mean @ fc2_w1^T + b1) @ fc2_w2^T + b2)
__global__ void k_head(const float* __restrict__ sum, const float* __restrict__ w1,
                       const float* __restrict__ bb1, const float* __restrict__ w2,
                       const float* __restrict__ bb2, float* __restrict__ out, float invN) {
  if (threadIdx.x == 0 && blockIdx.x == 0) {
    float xc[32];
#pragma unroll
    for (int k = 0; k < 32; ++k) xc[k] = sum[k] * invN;
    float t2 = bb2[0];
    for (int j = 0; j < 16; ++j) {
      float a = bb1[j];
#pragma unroll
      for (int k = 0; k < 32; ++k) a = fmaf(w1[j * 32 + k], xc[k], a);
      a = a > 0.f ? a : 0.f;
      t2 = fmaf(w2[j], a, t2);
    }
    out[0] = 1.f / (1.f + __expf(-t2));
  }
}

// sequential LSTM: ONE wave (64 lanes), zero barriers, zero LDS.
// lane l: j=l>>1, p=l&1. Owns rows p*32+j (i or f) and (2+p)*32+j (g or o).
// h broadcast via 32x v_readlane (h_j lives in lanes 2j,2j+1 — identical copies).
// Gate exchange: one quad_perm pair-swap + cndmask selects; both lanes of a pair
// redundantly compute the same cell update (no divergence, no cross-lane h fixup).
// Zx prefetched 8 deep in registers; no barriers -> vmcnt never force-drained.
__global__ void __launch_bounds__(64, 1) k_lstm(
    const float* __restrict__ Zx, const float* __restrict__ Whh,
    const float* __restrict__ fc1w, const float* __restrict__ fc1b,
    float* __restrict__ out, int N) {
  const int l = threadIdx.x;     // 0..63
  const int j = l >> 1;
  const int p = l & 1;
  const int rowA = p * 32 + j;         // i_j (p=0) or f_j (p=1)
  const int rowB = (2 + p) * 32 + j;   // g_j (p=0) or o_j (p=1)

  float wA[32], wB[32];
#pragma unroll
  for (int k = 0; k < 32; ++k) {
    wA[k] = Whh[rowA * 32 + k];
    wB[k] = Whh[rowB * 32 + k];
  }

  const float2* pz = (const float2*)Zx + l;   // lane's float2 column; step stride 64
  float2 zr[8];
#pragma unroll
  for (int s = 0; s < 8; ++s) zr[s] = pz[s * 64];

  float h = 0.f, c = 0.f;
  // N assumed divisible by 8 (N=20000)
  for (int t = 0; t < N; t += 8) {
#pragma unroll
    for (int s = 0; s < 8; ++s) {
      const int u = t + s;
      float zA = zr[s].x, zB = zr[s].y;
      int nu = u + 8; nu = (nu < N) ? nu : 0;   // clamped 8-deep prefetch
      zr[s] = pz[nu * 64];
      unsigned hbits = __float_as_uint(h);
#pragma unroll
      for (int k = 0; k < 32; ++k) {
        float hk = __uint_as_float(__builtin_amdgcn_readlane(hbits, 2 * k));
        zA = fmaf(wA[k], hk, zA);
        zB = fmaf(wB[k], hk, zB);
      }
      float xA = qperm<0xB1>(zA);   // pair-swap: even gets f-row val, odd gets i-row val
      float xB = qperm<0xB1>(zB);
      float zi = p ? xA : zA;
      float zf = p ? zA : xA;
      float zg = p ? xB : zB;
      float zo = p ? zB : xB;
      float ig = __builtin_amdgcn_rcpf(1.f + __expf(-zi));
      float fg = __builtin_amdgcn_rcpf(1.f + __expf(-zf));
      float og = __builtin_amdgcn_rcpf(1.f + __expf(-zo));
      float gg = 1.f - 2.f * __builtin_amdgcn_rcpf(__expf(2.f * zg) + 1.f);
      c = fmaf(fg, c, ig * gg);
      float tc = 1.f - 2.f * __builtin_amdgcn_rcpf(__expf(2.f * c) + 1.f);
      h = og * tc;   // identical in both lanes of the pair
    }
  }

  // c_j identical in lanes 2j, 2j+1 — mask odd lanes, wave-reduce
  float v = (p == 0) ? fmaxf(c, 0.f) * fc1w[j] : 0.f;
#pragma unroll
  for (int off = 32; off; off >>= 1) v += __shfl_down(v, off, 64);
  if (l == 0) out[1] = v + fc1b[0];
}

extern "C" void kernel_launch(void* const* d_in, const int* in_sizes, int n_in,
                              void* d_out, int out_size, void* d_ws, size_t ws_size,
                              hipStream_t stream) {
  const float* x    = (const float*)d_in[0];
  const int*   ei   = (const int*)d_in[1];
  // d_in[2] edge_attr unused (edge_dim=None)
  const float* W1   = (const float*)d_in[3];
  const float* a1s  = (const float*)d_in[4];
  const float* a1d  = (const float*)d_in[5];
  const float* b1   = (const float*)d_in[6];
  const float* W2   = (const float*)d_in[7];
  const float* a2s  = (const float*)d_in[8];
  const float* a2d  = (const float*)d_in[9];
  const float* b2   = (const float*)d_in[10];
  const float* Wih  = (const float*)d_in[11];
  const float* Whh  = (const float*)d_in[12];
  const float* bih  = (const float*)d_in[13];
  const float* bhh  = (const float*)d_in[14];
  const float* fc1w = (const float*)d_in[15];
  const float* fc1b = (const float*)d_in[16];
  const float* f2w1 = (const float*)d_in[17];
  const float* f2b1 = (const float*)d_in[18];
  const float* f2w2 = (const float*)d_in[19];
  const float* f2b2 = (const float*)d_in[20];

  const int N  = in_sizes[0] / IN_F;   // 20000
  const int E  = in_sizes[1] / 2;      // 640000
  const int EP = E + N;                // 660000 (with self-loops)

  float* ws = (float*)d_ws;
  float*    out1  = ws + OFF_OUT1;
  float*    out2  = ws + OFF_OUT2;
  float*    d1    = ws + OFF_D1;
  float*    d2    = ws + OFF_D2;
  float*    sum   = ws + OFF_SUM;
  unsigned* m1    = (unsigned*)(ws + OFF_M1);
  unsigned* m2    = (unsigned*)(ws + OFF_M2);
  float*    h1    = ws + OFF_H1;
  float*    h2    = ws + OFF_H2;
  float*    es1   = ws + OFF_ES1;
  float*    ed1   = ws + OFF_ED1;
  float*    es2   = ws + OFF_ES2;
  float*    ed2   = ws + OFF_ED2;
  float*    ebuf  = ws + OFF_EBUF;
  float*    Zx    = ws + OFF_ZX;

  // zero accumulators (out1,out2,denoms,sum are contiguous at ws start)
  hipMemsetAsync(d_ws, 0, (size_t)ZERO_FLOATS * 4, stream);
  k_initm<<<(N + 255) / 256, 256, 0, stream>>>(m1, m2, N);

  // ---- GAT layer 1 ----
  k_gemm1<<<N, 64, 0, stream>>>(x, W1, a1s, a1d, h1, es1, ed1);
  int eb = (EP + 255) / 256;
  k_emax<<<eb, 256, 0, stream>>>(ei, es1, ed1, ebuf, m1, E, EP);
  k_ep<<<eb, 256, 0, stream>>>(ei, ebuf, m1, d1, E, EP);
  k_aggr<64><<<((size_t)EP * 64 + 255) / 256, 256, 0, stream>>>(ei, ebuf, d1, h1, out1, E, EP);

  // ---- GAT layer 2 (relu + b1 fused into GEMM input) ----
  k_gemm2<<<(N + 1) / 2, 64, 0, stream>>>(out1, b1, W2, a2s, a2d, h2, es2, ed2, N);
  k_emax<<<eb, 256, 0, stream>>>(ei, es2, ed2, ebuf, m2, E, EP);
  k_ep<<<eb, 256, 0, stream>>>(ei, ebuf, m2, d2, E, EP);
  k_aggr<32><<<((size_t)EP * 32 + 255) / 256, 256, 0, stream>>>(ei, ebuf, d2, h2, out2, E, EP);

  // ---- LSTM input projection + mean pool + heads ----
  k_zx<<<N, 128, 0, stream>>>(out2, b2, Wih, bih, bhh, Zx);
  k_mean<<<64, 256, 0, stream>>>(out2, b2, sum, N);
  k_head<<<1, 64, 0, stream>>>(sum, f2w1, f2b1, f2w2, f2b2, (float*)d_out, 1.f / (float)N);
  k_lstm<<<1, 64, 0, stream>>>(Zx, Whh, fc1w, fc1b, (float*)d_out, N);
}

// Round 6
// 5742.966 us; speedup vs baseline: 1.8921x; 1.0188x over previous
//
#include <hip/hip_runtime.h>

#define IN_F 128
#define HID_F 64
#define OUT_F 32
#define ENC_NEG_INF 0x007FFFFFu
#define LOG2E 1.44269504088896340736f

// ---------------- workspace layout (float offsets) ----------------
// zeroed region first (single memset)
#define OFF_OUT1   0          // 1,280,000  (20000 x 64) aggregation accum L1
#define OFF_OUT2   1280000    // 640,000    (20000 x 32) aggregation accum L2
#define OFF_D1     1920000    // 20,000     softmax denom L1
#define OFF_D2     1940000    // 20,000     softmax denom L2
#define OFF_SUM    1960000    // 64         mean-pool partials (pad)
#define ZERO_FLOATS 1960064
#define OFF_M1     1960064    // 20,000  (unsigned, encoded max)
#define OFF_M2     1980064    // 20,000
#define OFF_H1     2000064    // 1,280,000  h1 = x@W1
#define OFF_H2     3280064    // 640,000    h2 = relu(out1+b1)@W2
#define OFF_ES1    3920064    // 20,000
#define OFF_ED1    3940064
#define OFF_ES2    3960064
#define OFF_ED2    3980064
#define OFF_EBUF   4000064    // 660,000    per-edge e / p
#define OFF_ZX     4660064    // 20000*128 + 1024 pad   LSTM input projection (PACKED+SCALED)
// total floats = 7,221,088 = 28.9 MB

__device__ __forceinline__ unsigned enc_f(float f) {
  unsigned b = __float_as_uint(f);
  return (b & 0x80000000u) ? ~b : (b | 0x80000000u);
}
__device__ __forceinline__ float dec_f(unsigned u) {
  unsigned b = (u & 0x80000000u) ? (u & 0x7FFFFFFFu) : ~u;
  return __uint_as_float(b);
}

// DPP quad_perm cross-lane (pure VALU): 0xB1 = swap within lane pairs (xor1)
template <int CTRL>
__device__ __forceinline__ float qperm(float x) {
  return __uint_as_float((unsigned)__builtin_amdgcn_update_dpp(
      0, (int)__float_as_uint(x), CTRL, 0xF, 0xF, true));
}

// init encoded -inf for segment-max buffers
__global__ void k_initm(unsigned* __restrict__ m1, unsigned* __restrict__ m2, int n) {
  int i = blockIdx.x * blockDim.x + threadIdx.x;
  if (i < n) { m1[i] = ENC_NEG_INF; m2[i] = ENC_NEG_INF; }
}

// h1 = x @ W1 ; es1 = h1 . a_src ; ed1 = h1 . a_dst   (one wave per node)
__global__ void k_gemm1(const float* __restrict__ x, const float* __restrict__ W1,
                        const float* __restrict__ a_src, const float* __restrict__ a_dst,
                        float* __restrict__ h1, float* __restrict__ es, float* __restrict__ ed) {
  int n = blockIdx.x;
  int f = threadIdx.x;           // 0..63
  const float* xr = x + n * IN_F;
  float acc = 0.f;
#pragma unroll 8
  for (int k = 0; k < IN_F; ++k) acc = fmaf(xr[k], W1[k * HID_F + f], acc);
  h1[n * HID_F + f] = acc;
  float s = acc * a_src[f];
  float d = acc * a_dst[f];
#pragma unroll
  for (int off = 32; off; off >>= 1) {
    s += __shfl_down(s, off, 64);
    d += __shfl_down(d, off, 64);
  }
  if (f == 0) { es[n] = s; ed[n] = d; }
}

// per-edge score e = leaky_relu(es[src]+ed[dst], 0.2); segment max via encoded atomicMax
__global__ void k_emax(const int* __restrict__ ei, const float* __restrict__ es,
                       const float* __restrict__ ed, float* __restrict__ ebuf,
                       unsigned* __restrict__ menc, int E, int EP) {
  int i = blockIdx.x * blockDim.x + threadIdx.x;
  if (i >= EP) return;
  int src, dst;
  if (i < E) { src = ei[i]; dst = ei[E + i]; } else { src = dst = i - E; }
  float e = es[src] + ed[dst];
  e = (e >= 0.f) ? e : 0.2f * e;
  ebuf[i] = e;
  atomicMax(&menc[dst], enc_f(e));
}

// p = exp(e - m[dst]); denom[dst] += p
__global__ void k_ep(const int* __restrict__ ei, float* __restrict__ ebuf,
                     const unsigned* __restrict__ menc, float* __restrict__ denom,
                     int E, int EP) {
  int i = blockIdx.x * blockDim.x + threadIdx.x;
  if (i >= EP) return;
  int dst = (i < E) ? ei[E + i] : (i - E);
  float p = __expf(ebuf[i] - dec_f(menc[dst]));
  ebuf[i] = p;
  atomicAdd(&denom[dst], p);
}

// out[dst] += (p/denom[dst]) * h[src]   — F lanes per edge, coalesced gather+atomic
template <int F>
__global__ void k_aggr(const int* __restrict__ ei, const float* __restrict__ ebuf,
                       const float* __restrict__ denom, const float* __restrict__ h,
                       float* __restrict__ out, int E, int EP) {
  int gt = blockIdx.x * blockDim.x + threadIdx.x;
  int lane = gt % F;
  int e = gt / F;
  if (e >= EP) return;
  int src, dst;
  if (e < E) { src = ei[e]; dst = ei[E + e]; } else { src = dst = e - E; }
  float alpha = ebuf[e] / denom[dst];
  atomicAdd(&out[dst * F + lane], alpha * h[src * F + lane]);
}

// h2 = relu(out1+b1) @ W2 ; es2/ed2 reductions.  64 threads = 2 nodes/block.
__global__ void k_gemm2(const float* __restrict__ out1, const float* __restrict__ b1,
                        const float* __restrict__ W2, const float* __restrict__ a_src,
                        const float* __restrict__ a_dst, float* __restrict__ h2,
                        float* __restrict__ es, float* __restrict__ ed, int N) {
  int lane = threadIdx.x;
  int f = lane & 31;
  int n = blockIdx.x * 2 + (lane >> 5);
  if (n >= N) return;
  const float* r = out1 + n * HID_F;
  float acc = 0.f;
#pragma unroll 8
  for (int k = 0; k < HID_F; ++k) {
    float v = r[k] + b1[k];
    v = v > 0.f ? v : 0.f;
    acc = fmaf(v, W2[k * OUT_F + f], acc);
  }
  h2[n * OUT_F + f] = acc;
  float s = acc * a_src[f];
  float d = acc * a_dst[f];
#pragma unroll
  for (int off = 16; off; off >>= 1) {
    s += __shfl_down(s, off, 32);
    d += __shfl_down(d, off, 32);
  }
  if (f == 0) { es[n] = s; ed[n] = d; }
}

// Zx packed+scaled for single-wave LSTM: row r (gate-major: i=0..31,f=..63,g=..95,o=..127)
//   j=r&31, gate=r>>5 ; p=gate&1, e=gate>>1 ; pos = j*4 + p*2 + e
// LSTM lane l=j*2+p reads float2 at t*128 + l*2 : .x = gate p (i/f), .y = gate 2+p (g/o)
// SCALE FOLDING: rows i,f,o are premultiplied by log2(e), row g by 2*log2(e),
// so the LSTM can use exp2 directly (sigmoid = rcp(1+exp2(-z')), tanh = 2*sig(2x)-1).
__global__ void k_zx(const float* __restrict__ out2, const float* __restrict__ b2,
                     const float* __restrict__ Wih, const float* __restrict__ bih,
                     const float* __restrict__ bhh, float* __restrict__ Zx) {
  int r = threadIdx.x;   // 0..127
  int t = blockIdx.x;
  const float* xr = out2 + t * OUT_F;
  float acc = bih[r] + bhh[r];
#pragma unroll
  for (int k = 0; k < OUT_F; ++k) acc = fmaf(xr[k] + b2[k], Wih[r * OUT_F + k], acc);
  float scl = (r >= 64 && r < 96) ? 2.f * LOG2E : LOG2E;   // g-rows get 2L
  int pos = ((r & 31) << 2) | (((r >> 5) & 1) << 1) | (r >> 6);
  Zx[t * 128 + pos] = acc * scl;
}

// mean-pool partial sums of (out2 + b2)
__global__ void k_mean(const float* __restrict__ out2, const float* __restrict__ b2,
                       float* __restrict__ sum, int N) {
  int k = threadIdx.x & 31;
  int row = threadIdx.x >> 5;   // 0..7
  float acc = 0.f;
  for (int n = blockIdx.x * 8 + row; n < N; n += gridDim.x * 8)
    acc += out2[n * OUT_F + k] + b2[k];
  __shared__ float s[256];
  s[threadIdx.x] = acc;
  __syncthreads();
  if (threadIdx.x < 32) {
    float tot = 0.f;
#pragma unroll
    for (int j = 0; j < 8; ++j) tot += s[j * 32 + k];
    atomicAdd(&sum[k], tot);
  }
}

// classification head: out[0] = sigmoid(relu(mean @ fc2_w1^T + b1) @ fc2_w2^T + b2)
__global__ void k_head(const float* __restrict__ sum, const float* __restrict__ w1,
                       const float* __restrict__ bb1, const float* __restrict__ w2,
                       const float* __restrict__ bb2, float* __restrict__ out, float invN) {
  if (threadIdx.x == 0 && blockIdx.x == 0) {
    float xc[32];
#pragma unroll
    for (int k = 0; k < 32; ++k) xc[k] = sum[k] * invN;
    float t2 = bb2[0];
    for (int j = 0; j < 16; ++j) {
      float a = bb1[j];
#pragma unroll
      for (int k = 0; k < 32; ++k) a = fmaf(w1[j * 32 + k], xc[k], a);
      a = a > 0.f ? a : 0.f;
      t2 = fmaf(w2[j], a, t2);
    }
    out[0] = 1.f / (1.f + __expf(-t2));
  }
}

// sequential LSTM: ONE wave, zero barriers, zero LDS.
// lane l: j=l>>1, p=l&1. Owns rows p*32+j (i/f, scale L) and (2+p)*32+j (g/o, scale 2L/L).
// h broadcast via 32x v_readlane of EVEN lanes (h valid only on even lanes).
// Gate math is lane-split: one exp2 computes sig(zi) on even / sig(zf) on odd;
// a second computes sig(2*zg) on even / sig(zo) on odd. Two qperm pair-swaps
// deliver fg/og to even lanes. Odd-lane c/h are garbage by design (never read).
// Zx prefetched 8 deep with UNCLAMPED affine addressing (pad covers overrun) ->
// strength-reduced pointers + precise vmcnt tracking.
__global__ void __launch_bounds__(64, 1) k_lstm(
    const float* __restrict__ Zx, const float* __restrict__ Whh,
    const float* __restrict__ fc1w, const float* __restrict__ fc1b,
    float* __restrict__ out, int N) {
  const int l = threadIdx.x;     // 0..63
  const int j = l >> 1;
  const int p = l & 1;
  const int rowA = p * 32 + j;         // i_j (p=0) or f_j (p=1)
  const int rowB = (2 + p) * 32 + j;   // g_j (p=0) or o_j (p=1)
  const float sclA = LOG2E;
  const float sclB = p ? LOG2E : 2.f * LOG2E;

  float wA[32], wB[32];
#pragma unroll
  for (int k = 0; k < 32; ++k) {
    wA[k] = Whh[rowA * 32 + k] * sclA;
    wB[k] = Whh[rowB * 32 + k] * sclB;
  }

  const float2* pz = (const float2*)Zx + l;   // lane's float2 column; step stride 64
  float2 zr[8];
#pragma unroll
  for (int s = 0; s < 8; ++s) zr[s] = pz[s * 64];

  const float n2L = -2.f * LOG2E;
  float h = 0.f, c = 0.f;
  // N divisible by 8 (N=20000)
  for (int t = 0; t < N; t += 8) {
#pragma unroll
    for (int s = 0; s < 8; ++s) {
      float zA = zr[s].x, zB = zr[s].y;
      zr[s] = pz[(t + s + 8) * 64];   // unclamped affine prefetch (pad covers tail)
      unsigned hbits = __float_as_uint(h);
#pragma unroll
      for (int k = 0; k < 32; ++k) {
        float hk = __uint_as_float(__builtin_amdgcn_readlane(hbits, 2 * k));
        zA = fmaf(wA[k], hk, zA);
        zB = fmaf(wB[k], hk, zB);
      }
      // even: zA=L*zi, zB=2L*zg ; odd: zA=L*zf, zB=L*zo
      float sA = __builtin_amdgcn_rcpf(1.f + exp2f(-zA));  // even: ig ; odd: fg
      float sB = __builtin_amdgcn_rcpf(1.f + exp2f(-zB));  // even: sig(2zg) ; odd: og
      float fgx = qperm<0xB1>(sA);          // even lane receives fg
      float ogx = qperm<0xB1>(sB);          // even lane receives og
      float gg = fmaf(2.f, sB, -1.f);       // even: tanh(zg)
      c = fmaf(fgx, c, sA * gg);            // valid on even lanes only
      float r3 = __builtin_amdgcn_rcpf(1.f + exp2f(n2L * c));
      float tc = fmaf(2.f, r3, -1.f);       // tanh(c)
      h = ogx * tc;                         // valid on even lanes only
    }
  }

  // c valid in even lanes; mask odd lanes, wave-reduce
  float v = (p == 0) ? fmaxf(c, 0.f) * fc1w[j] : 0.f;
#pragma unroll
  for (int off = 32; off; off >>= 1) v += __shfl_down(v, off, 64);
  if (l == 0) out[1] = v + fc1b[0];
}

extern "C" void kernel_launch(void* const* d_in, const int* in_sizes, int n_in,
                              void* d_out, int out_size, void* d_ws, size_t ws_size,
                              hipStream_t stream) {
  const float* x    = (const float*)d_in[0];
  const int*   ei   = (const int*)d_in[1];
  // d_in[2] edge_attr unused (edge_dim=None)
  const float* W1   = (const float*)d_in[3];
  const float* a1s  = (const float*)d_in[4];
  const float* a1d  = (const float*)d_in[5];
  const float* b1   = (const float*)d_in[6];
  const float* W2   = (const float*)d_in[7];
  const float* a2s  = (const float*)d_in[8];
  const float* a2d  = (const float*)d_in[9];
  const float* b2   = (const float*)d_in[10];
  const float* Wih  = (const float*)d_in[11];
  const float* Whh  = (const float*)d_in[12];
  const float* bih  = (const float*)d_in[13];
  const float* bhh  = (const float*)d_in[14];
  const float* fc1w = (const float*)d_in[15];
  const float* fc1b = (const float*)d_in[16];
  const float* f2w1 = (const float*)d_in[17];
  const float* f2b1 = (const float*)d_in[18];
  const float* f2w2 = (const float*)d_in[19];
  const float* f2b2 = (const float*)d_in[20];

  const int N  = in_sizes[0] / IN_F;   // 20000
  const int E  = in_sizes[1] / 2;      // 640000
  const int EP = E + N;                // 660000 (with self-loops)

  float* ws = (float*)d_ws;
  float*    out1  = ws + OFF_OUT1;
  float*    out2  = ws + OFF_OUT2;
  float*    d1    = ws + OFF_D1;
  float*    d2    = ws + OFF_D2;
  float*    sum   = ws + OFF_SUM;
  unsigned* m1    = (unsigned*)(ws + OFF_M1);
  unsigned* m2    = (unsigned*)(ws + OFF_M2);
  float*    h1    = ws + OFF_H1;
  float*    h2    = ws + OFF_H2;
  float*    es1   = ws + OFF_ES1;
  float*    ed1   = ws + OFF_ED1;
  float*    es2   = ws + OFF_ES2;
  float*    ed2   = ws + OFF_ED2;
  float*    ebuf  = ws + OFF_EBUF;
  float*    Zx    = ws + OFF_ZX;

  // zero accumulators (out1,out2,denoms,sum are contiguous at ws start)
  hipMemsetAsync(d_ws, 0, (size_t)ZERO_FLOATS * 4, stream);
  k_initm<<<(N + 255) / 256, 256, 0, stream>>>(m1, m2, N);

  // ---- GAT layer 1 ----
  k_gemm1<<<N, 64, 0, stream>>>(x, W1, a1s, a1d, h1, es1, ed1);
  int eb = (EP + 255) / 256;
  k_emax<<<eb, 256, 0, stream>>>(ei, es1, ed1, ebuf, m1, E, EP);
  k_ep<<<eb, 256, 0, stream>>>(ei, ebuf, m1, d1, E, EP);
  k_aggr<64><<<((size_t)EP * 64 + 255) / 256, 256, 0, stream>>>(ei, ebuf, d1, h1, out1, E, EP);

  // ---- GAT layer 2 (relu + b1 fused into GEMM input) ----
  k_gemm2<<<(N + 1) / 2, 64, 0, stream>>>(out1, b1, W2, a2s, a2d, h2, es2, ed2, N);
  k_emax<<<eb, 256, 0, stream>>>(ei, es2, ed2, ebuf, m2, E, EP);
  k_ep<<<eb, 256, 0, stream>>>(ei, ebuf, m2, d2, E, EP);
  k_aggr<32><<<((size_t)EP * 32 + 255) / 256, 256, 0, stream>>>(ei, ebuf, d2, h2, out2, E, EP);

  // ---- LSTM input projection + mean pool + heads ----
  k_zx<<<N, 128, 0, stream>>>(out2, b2, Wih, bih, bhh, Zx);
  k_mean<<<64, 256, 0, stream>>>(out2, b2, sum, N);
  k_head<<<1, 64, 0, stream>>>(sum, f2w1, f2b1, f2w2, f2b2, (float*)d_out, 1.f / (float)N);
  k_lstm<<<1, 64, 0, stream>>>(Zx, Whh, fc1w, fc1b, (float*)d_out, N);
}

// Round 7
// 5206.797 us; speedup vs baseline: 2.0869x; 1.1030x over previous
//
#include <hip/hip_runtime.h>

#define IN_F 128
#define HID_F 64
#define OUT_F 32
#define ENC_NEG_INF 0x007FFFFFu
#define LOG2E 1.44269504088896340736f

// ---------------- workspace layout (float offsets) ----------------
// zeroed region first (single memset)
#define OFF_OUT1   0          // 1,280,000  (20000 x 64) aggregation accum L1
#define OFF_OUT2   1280000    // 640,000    (20000 x 32) aggregation accum L2
#define OFF_D1     1920000    // 20,000     softmax denom L1
#define OFF_D2     1940000    // 20,000     softmax denom L2
#define OFF_SUM    1960000    // 64         mean-pool partials (pad)
#define ZERO_FLOATS 1960064
#define OFF_M1     1960064    // 20,000  (unsigned, encoded max)
#define OFF_M2     1980064    // 20,000
#define OFF_H1     2000064    // 1,280,000  h1 = x@W1
#define OFF_H2     3280064    // 640,000    h2 = relu(out1+b1)@W2
#define OFF_ES1    3920064    // 20,000
#define OFF_ED1    3940064
#define OFF_ES2    3960064
#define OFF_ED2    3980064
#define OFF_EBUF   4000064    // 660,000    per-edge e / p
#define OFF_ZX     4660064    // 20000*128 + 1024 pad   LSTM input projection (PACKED+SCALED)
// total floats = 7,221,088 = 28.9 MB

__device__ __forceinline__ unsigned enc_f(float f) {
  unsigned b = __float_as_uint(f);
  return (b & 0x80000000u) ? ~b : (b | 0x80000000u);
}
__device__ __forceinline__ float dec_f(unsigned u) {
  unsigned b = (u & 0x80000000u) ? (u & 0x7FFFFFFFu) : ~u;
  return __uint_as_float(b);
}

// DPP quad_perm cross-lane (pure VALU): 0xB1 = swap within lane pairs (xor1)
template <int CTRL>
__device__ __forceinline__ float qperm(float x) {
  return __uint_as_float((unsigned)__builtin_amdgcn_update_dpp(
      0, (int)__float_as_uint(x), CTRL, 0xF, 0xF, true));
}

// init encoded -inf for segment-max buffers
__global__ void k_initm(unsigned* __restrict__ m1, unsigned* __restrict__ m2, int n) {
  int i = blockIdx.x * blockDim.x + threadIdx.x;
  if (i < n) { m1[i] = ENC_NEG_INF; m2[i] = ENC_NEG_INF; }
}

// h1 = x @ W1 ; es1 = h1 . a_src ; ed1 = h1 . a_dst   (one wave per node)
__global__ void k_gemm1(const float* __restrict__ x, const float* __restrict__ W1,
                        const float* __restrict__ a_src, const float* __restrict__ a_dst,
                        float* __restrict__ h1, float* __restrict__ es, float* __restrict__ ed) {
  int n = blockIdx.x;
  int f = threadIdx.x;           // 0..63
  const float* xr = x + n * IN_F;
  float acc = 0.f;
#pragma unroll 8
  for (int k = 0; k < IN_F; ++k) acc = fmaf(xr[k], W1[k * HID_F + f], acc);
  h1[n * HID_F + f] = acc;
  float s = acc * a_src[f];
  float d = acc * a_dst[f];
#pragma unroll
  for (int off = 32; off; off >>= 1) {
    s += __shfl_down(s, off, 64);
    d += __shfl_down(d, off, 64);
  }
  if (f == 0) { es[n] = s; ed[n] = d; }
}

// per-edge score e = leaky_relu(es[src]+ed[dst], 0.2); segment max via encoded atomicMax
__global__ void k_emax(const int* __restrict__ ei, const float* __restrict__ es,
                       const float* __restrict__ ed, float* __restrict__ ebuf,
                       unsigned* __restrict__ menc, int E, int EP) {
  int i = blockIdx.x * blockDim.x + threadIdx.x;
  if (i >= EP) return;
  int src, dst;
  if (i < E) { src = ei[i]; dst = ei[E + i]; } else { src = dst = i - E; }
  float e = es[src] + ed[dst];
  e = (e >= 0.f) ? e : 0.2f * e;
  ebuf[i] = e;
  atomicMax(&menc[dst], enc_f(e));
}

// p = exp(e - m[dst]); denom[dst] += p
__global__ void k_ep(const int* __restrict__ ei, float* __restrict__ ebuf,
                     const unsigned* __restrict__ menc, float* __restrict__ denom,
                     int E, int EP) {
  int i = blockIdx.x * blockDim.x + threadIdx.x;
  if (i >= EP) return;
  int dst = (i < E) ? ei[E + i] : (i - E);
  float p = __expf(ebuf[i] - dec_f(menc[dst]));
  ebuf[i] = p;
  atomicAdd(&denom[dst], p);
}

// out[dst] += (p/denom[dst]) * h[src]   — F lanes per edge, coalesced gather+atomic
template <int F>
__global__ void k_aggr(const int* __restrict__ ei, const float* __restrict__ ebuf,
                       const float* __restrict__ denom, const float* __restrict__ h,
                       float* __restrict__ out, int E, int EP) {
  int gt = blockIdx.x * blockDim.x + threadIdx.x;
  int lane = gt % F;
  int e = gt / F;
  if (e >= EP) return;
  int src, dst;
  if (e < E) { src = ei[e]; dst = ei[E + e]; } else { src = dst = e - E; }
  float alpha = ebuf[e] / denom[dst];
  atomicAdd(&out[dst * F + lane], alpha * h[src * F + lane]);
}

// h2 = relu(out1+b1) @ W2 ; es2/ed2 reductions.  64 threads = 2 nodes/block.
__global__ void k_gemm2(const float* __restrict__ out1, const float* __restrict__ b1,
                        const float* __restrict__ W2, const float* __restrict__ a_src,
                        const float* __restrict__ a_dst, float* __restrict__ h2,
                        float* __restrict__ es, float* __restrict__ ed, int N) {
  int lane = threadIdx.x;
  int f = lane & 31;
  int n = blockIdx.x * 2 + (lane >> 5);
  if (n >= N) return;
  const float* r = out1 + n * HID_F;
  float acc = 0.f;
#pragma unroll 8
  for (int k = 0; k < HID_F; ++k) {
    float v = r[k] + b1[k];
    v = v > 0.f ? v : 0.f;
    acc = fmaf(v, W2[k * OUT_F + f], acc);
  }
  h2[n * OUT_F + f] = acc;
  float s = acc * a_src[f];
  float d = acc * a_dst[f];
#pragma unroll
  for (int off = 16; off; off >>= 1) {
    s += __shfl_down(s, off, 32);
    d += __shfl_down(d, off, 32);
  }
  if (f == 0) { es[n] = s; ed[n] = d; }
}

// Zx packed+scaled for single-wave LSTM: row r (gate-major: i=0..31,f=..63,g=..95,o=..127)
//   j=r&31, gate=r>>5 ; p=gate&1, e=gate>>1 ; pos = j*4 + p*2 + e
// LSTM lane l=j*2+p reads float2 at t*128 + l*2 : .x = gate p (i/f), .y = gate 2+p (g/o)
// SCALE FOLDING: rows i,f,o are premultiplied by log2(e), row g by 2*log2(e),
// so the LSTM can use exp2 directly (sigmoid = rcp(1+exp2(-z')), tanh = 2*sig(2x)-1).
__global__ void k_zx(const float* __restrict__ out2, const float* __restrict__ b2,
                     const float* __restrict__ Wih, const float* __restrict__ bih,
                     const float* __restrict__ bhh, float* __restrict__ Zx) {
  int r = threadIdx.x;   // 0..127
  int t = blockIdx.x;
  const float* xr = out2 + t * OUT_F;
  float acc = bih[r] + bhh[r];
#pragma unroll
  for (int k = 0; k < OUT_F; ++k) acc = fmaf(xr[k] + b2[k], Wih[r * OUT_F + k], acc);
  float scl = (r >= 64 && r < 96) ? 2.f * LOG2E : LOG2E;   // g-rows get 2L
  int pos = ((r & 31) << 2) | (((r >> 5) & 1) << 1) | (r >> 6);
  Zx[t * 128 + pos] = acc * scl;
}

// mean-pool partial sums of (out2 + b2)
__global__ void k_mean(const float* __restrict__ out2, const float* __restrict__ b2,
                       float* __restrict__ sum, int N) {
  int k = threadIdx.x & 31;
  int row = threadIdx.x >> 5;   // 0..7
  float acc = 0.f;
  for (int n = blockIdx.x * 8 + row; n < N; n += gridDim.x * 8)
    acc += out2[n * OUT_F + k] + b2[k];
  __shared__ float s[256];
  s[threadIdx.x] = acc;
  __syncthreads();
  if (threadIdx.x < 32) {
    float tot = 0.f;
#pragma unroll
    for (int j = 0; j < 8; ++j) tot += s[j * 32 + k];
    atomicAdd(&sum[k], tot);
  }
}

// classification head: out[0] = sigmoid(relu(mean @ fc2_w1^T + b1) @ fc2_w2^T + b2)
__global__ void k_head(const float* __restrict__ sum, const float* __restrict__ w1,
                       const float* __restrict__ bb1, const float* __restrict__ w2,
                       const float* __restrict__ bb2, float* __restrict__ out, float invN) {
  if (threadIdx.x == 0 && blockIdx.x == 0) {
    float xc[32];
#pragma unroll
    for (int k = 0; k < 32; ++k) xc[k] = sum[k] * invN;
    float t2 = bb2[0];
    for (int j = 0; j < 16; ++j) {
      float a = bb1[j];
#pragma unroll
      for (int k = 0; k < 32; ++k) a = fmaf(w1[j * 32 + k], xc[k], a);
      a = a > 0.f ? a : 0.f;
      t2 = fmaf(w2[j], a, t2);
    }
    out[0] = 1.f / (1.f + __expf(-t2));
  }
}

// sequential LSTM: ONE wave, zero barriers, zero LDS.
// lane l: j=l>>1, p=l&1. Owns rows p*32+j (i/f, scale L) and (2+p)*32+j (g/o, scale 2L/L).
// Round-6 change: BATCH the 32 readlanes into wave-uniform hk[0..31] (SGPRs) with a
// sched_barrier fence, so readlanes pipeline (1 hazard total, not 32), then run the
// 64 FMAs as 4 independent 16-deep chains (latency ~70cy, hidden under issue).
// Gate math lane-split (3 exp2 + 3 rcp); odd-lane c/h garbage by design (never read).
__global__ void __launch_bounds__(64, 1) k_lstm(
    const float* __restrict__ Zx, const float* __restrict__ Whh,
    const float* __restrict__ fc1w, const float* __restrict__ fc1b,
    float* __restrict__ out, int N) {
  const int l = threadIdx.x;     // 0..63
  const int j = l >> 1;
  const int p = l & 1;
  const int rowA = p * 32 + j;         // i_j (p=0) or f_j (p=1)
  const int rowB = (2 + p) * 32 + j;   // g_j (p=0) or o_j (p=1)
  const float sclA = LOG2E;
  const float sclB = p ? LOG2E : 2.f * LOG2E;

  float wA[32], wB[32];
#pragma unroll
  for (int k = 0; k < 32; ++k) {
    wA[k] = Whh[rowA * 32 + k] * sclA;
    wB[k] = Whh[rowB * 32 + k] * sclB;
  }

  const float2* pz = (const float2*)Zx + l;   // lane's float2 column; step stride 64
  float2 zr[8];
#pragma unroll
  for (int s = 0; s < 8; ++s) zr[s] = pz[s * 64];

  const float n2L = -2.f * LOG2E;
  float h = 0.f, c = 0.f;
  // N divisible by 8 (N=20000)
  for (int t = 0; t < N; t += 8) {
#pragma unroll
    for (int s = 0; s < 8; ++s) {
      float zA = zr[s].x, zB = zr[s].y;
      zr[s] = pz[(t + s + 8) * 64];   // unclamped affine prefetch (pad covers tail)
      unsigned hbits = __float_as_uint(h);
      // ---- batched broadcast: 32 independent readlanes -> SGPRs ----
      float hk[32];
#pragma unroll
      for (int k = 0; k < 32; ++k)
        hk[k] = __uint_as_float(__builtin_amdgcn_readlane(hbits, 2 * k));
      __builtin_amdgcn_sched_barrier(0);   // keep readlane batch ahead of FMA stream
      // ---- 4 independent 16-deep FMA chains ----
      float a0 = zA, a1 = 0.f, b0 = zB, b1 = 0.f;
#pragma unroll
      for (int k = 0; k < 16; ++k) {
        a0 = fmaf(wA[k], hk[k], a0);
        b0 = fmaf(wB[k], hk[k], b0);
        a1 = fmaf(wA[16 + k], hk[16 + k], a1);
        b1 = fmaf(wB[16 + k], hk[16 + k], b1);
      }
      zA = a0 + a1;
      zB = b0 + b1;
      // even: zA=L*zi, zB=2L*zg ; odd: zA=L*zf, zB=L*zo
      float sA = __builtin_amdgcn_rcpf(1.f + exp2f(-zA));  // even: ig ; odd: fg
      float sB = __builtin_amdgcn_rcpf(1.f + exp2f(-zB));  // even: sig(2zg) ; odd: og
      float fgx = qperm<0xB1>(sA);          // even lane receives fg
      float ogx = qperm<0xB1>(sB);          // even lane receives og
      float gg = fmaf(2.f, sB, -1.f);       // even: tanh(zg)
      c = fmaf(fgx, c, sA * gg);            // valid on even lanes only
      float r3 = __builtin_amdgcn_rcpf(1.f + exp2f(n2L * c));
      float tc = fmaf(2.f, r3, -1.f);       // tanh(c)
      h = ogx * tc;                         // valid on even lanes only
    }
  }

  // c valid in even lanes; mask odd lanes, wave-reduce
  float v = (p == 0) ? fmaxf(c, 0.f) * fc1w[j] : 0.f;
#pragma unroll
  for (int off = 32; off; off >>= 1) v += __shfl_down(v, off, 64);
  if (l == 0) out[1] = v + fc1b[0];
}

extern "C" void kernel_launch(void* const* d_in, const int* in_sizes, int n_in,
                              void* d_out, int out_size, void* d_ws, size_t ws_size,
                              hipStream_t stream) {
  const float* x    = (const float*)d_in[0];
  const int*   ei   = (const int*)d_in[1];
  // d_in[2] edge_attr unused (edge_dim=None)
  const float* W1   = (const float*)d_in[3];
  const float* a1s  = (const float*)d_in[4];
  const float* a1d  = (const float*)d_in[5];
  const float* b1   = (const float*)d_in[6];
  const float* W2   = (const float*)d_in[7];
  const float* a2s  = (const float*)d_in[8];
  const float* a2d  = (const float*)d_in[9];
  const float* b2   = (const float*)d_in[10];
  const float* Wih  = (const float*)d_in[11];
  const float* Whh  = (const float*)d_in[12];
  const float* bih  = (const float*)d_in[13];
  const float* bhh  = (const float*)d_in[14];
  const float* fc1w = (const float*)d_in[15];
  const float* fc1b = (const float*)d_in[16];
  const float* f2w1 = (const float*)d_in[17];
  const float* f2b1 = (const float*)d_in[18];
  const float* f2w2 = (const float*)d_in[19];
  const float* f2b2 = (const float*)d_in[20];

  const int N  = in_sizes[0] / IN_F;   // 20000
  const int E  = in_sizes[1] / 2;      // 640000
  const int EP = E + N;                // 660000 (with self-loops)

  float* ws = (float*)d_ws;
  float*    out1  = ws + OFF_OUT1;
  float*    out2  = ws + OFF_OUT2;
  float*    d1    = ws + OFF_D1;
  float*    d2    = ws + OFF_D2;
  float*    sum   = ws + OFF_SUM;
  unsigned* m1    = (unsigned*)(ws + OFF_M1);
  unsigned* m2    = (unsigned*)(ws + OFF_M2);
  float*    h1    = ws + OFF_H1;
  float*    h2    = ws + OFF_H2;
  float*    es1   = ws + OFF_ES1;
  float*    ed1   = ws + OFF_ED1;
  float*    es2   = ws + OFF_ES2;
  float*    ed2   = ws + OFF_ED2;
  float*    ebuf  = ws + OFF_EBUF;
  float*    Zx    = ws + OFF_ZX;

  // zero accumulators (out1,out2,denoms,sum are contiguous at ws start)
  hipMemsetAsync(d_ws, 0, (size_t)ZERO_FLOATS * 4, stream);
  k_initm<<<(N + 255) / 256, 256, 0, stream>>>(m1, m2, N);

  // ---- GAT layer 1 ----
  k_gemm1<<<N, 64, 0, stream>>>(x, W1, a1s, a1d, h1, es1, ed1);
  int eb = (EP + 255) / 256;
  k_emax<<<eb, 256, 0, stream>>>(ei, es1, ed1, ebuf, m1, E, EP);
  k_ep<<<eb, 256, 0, stream>>>(ei, ebuf, m1, d1, E, EP);
  k_aggr<64><<<((size_t)EP * 64 + 255) / 256, 256, 0, stream>>>(ei, ebuf, d1, h1, out1, E, EP);

  // ---- GAT layer 2 (relu + b1 fused into GEMM input) ----
  k_gemm2<<<(N + 1) / 2, 64, 0, stream>>>(out1, b1, W2, a2s, a2d, h2, es2, ed2, N);
  k_emax<<<eb, 256, 0, stream>>>(ei, es2, ed2, ebuf, m2, E, EP);
  k_ep<<<eb, 256, 0, stream>>>(ei, ebuf, m2, d2, E, EP);
  k_aggr<32><<<((size_t)EP * 32 + 255) / 256, 256, 0, stream>>>(ei, ebuf, d2, h2, out2, E, EP);

  // ---- LSTM input projection + mean pool + heads ----
  k_zx<<<N, 128, 0, stream>>>(out2, b2, Wih, bih, bhh, Zx);
  k_mean<<<64, 256, 0, stream>>>(out2, b2, sum, N);
  k_head<<<1, 64, 0, stream>>>(sum, f2w1, f2b1, f2w2, f2b2, (float*)d_out, 1.f / (float)N);
  k_lstm<<<1, 64, 0, stream>>>(Zx, Whh, fc1w, fc1b, (float*)d_out, N);
}